// Round 14
// baseline (899.974 us; speedup 1.0000x reference)
//
#include <hip/hip_runtime.h>

#define NN 200000
#define NE 3200000
#define NWG 768
#define NSLOT 32
static constexpr float EPSV = 1e-5f;

// ---------------- CSR build: 2-level bucket sort ----------------
__global__ void k_cnt_prep(const int* __restrict__ ei, int* __restrict__ bktCnt,
                           const float* __restrict__ x, const float* __restrict__ pos,
                           float4* __restrict__ feat, float* __restrict__ xstats){
  __shared__ int cnt[256];
  __shared__ float sv[256], sq[256];
  int t = threadIdx.x;
  cnt[t] = 0;
  int i = blockIdx.x*256 + t;
  float xf = 0.f;
  if (i < NN){
    xf = x[i];
    feat[i] = make_float4(xf, pos[3*i], pos[3*i+1], 0.f);
  }
  sv[t] = (i < NN) ? xf : 0.f;
  sq[t] = sv[t]*sv[t];
  __syncthreads();
  int tile = blockIdx.x*4096;
  #pragma unroll
  for (int k = 0; k < 16; ++k){
    int e = tile + k*256 + t;
    if (e < NE) atomicAdd(&cnt[ei[NE+e]>>10], 1);
  }
  for (int o = 128; o > 0; o >>= 1){
    __syncthreads();
    if (t < o){ sv[t]+=sv[t+o]; sq[t]+=sq[t+o]; }
  }
  __syncthreads();
  if (t == 0){ atomicAdd(&xstats[0], sv[0]); atomicAdd(&xstats[1], sq[0]); }
  if (cnt[t]) atomicAdd(&bktCnt[t], cnt[t]);
}

__global__ void k_bktscan(const int* __restrict__ bktCnt, int* __restrict__ bktBase,
                          int* __restrict__ bktCur, int* __restrict__ off){
  __shared__ int s[256];
  int t = threadIdx.x;
  int v = bktCnt[t];
  s[t] = v; __syncthreads();
  for (int o = 1; o < 256; o <<= 1){
    int xv = (t >= o) ? s[t-o] : 0;
    __syncthreads(); s[t] += xv; __syncthreads();
  }
  int excl = s[t] - v;
  bktBase[t] = excl;
  bktCur[t]  = excl;
  if (t == 0){ bktBase[256] = NE; off[NN] = NE; }
}

__global__ void k_part1(const int* __restrict__ ei, int* __restrict__ bktCur,
                        int* __restrict__ pairs){
  __shared__ int cnt[256]; __shared__ int base[256]; __shared__ int rank[256];
  int t = threadIdx.x;   // 1024 threads
  if (t < 256) cnt[t] = 0;
  __syncthreads();
  int tile = blockIdx.x*16384;
  #pragma unroll
  for (int k = 0; k < 16; ++k){
    int e = tile + k*1024 + t;
    if (e < NE) atomicAdd(&cnt[ei[NE+e]>>10], 1);
  }
  __syncthreads();
  if (t < 256){
    base[t] = cnt[t] ? atomicAdd(&bktCur[t], cnt[t]) : 0;
    rank[t] = 0;
  }
  __syncthreads();
  #pragma unroll
  for (int k = 0; k < 16; ++k){
    int e = tile + k*1024 + t;
    if (e < NE){
      int d = ei[NE+e], s = ei[e];
      int b = d >> 10;
      int r = atomicAdd(&rank[b], 1);
      pairs[base[b] + r] = (s<<10) | (d & 1023);
    }
  }
}

__global__ void k_part2(const int* __restrict__ pairs, const int* __restrict__ bktBase,
                        int* __restrict__ off, int* __restrict__ srcs){
  __shared__ int hist[1024]; __shared__ int cur[1024];
  int b = blockIdx.x, t = threadIdx.x;
  int p0 = bktBase[b], p1 = bktBase[b+1];
  int cntB = p1 - p0;
  int dstBase = b << 10;
  int width = min(1024, NN - dstBase);
  hist[t] = 0; __syncthreads();
  for (int i = t; i < cntB; i += 1024) atomicAdd(&hist[pairs[p0+i] & 1023], 1);
  __syncthreads();
  int h0 = hist[t];
  for (int o = 1; o < 1024; o <<= 1){
    int xv = (t >= o) ? hist[t-o] : 0;
    __syncthreads(); hist[t] += xv; __syncthreads();
  }
  int excl = hist[t] - h0;
  if (t < width) off[dstBase + t] = p0 + excl;
  cur[t] = excl; __syncthreads();
  for (int i = t; i < cntB; i += 1024){
    int v = pairs[p0+i];
    int r = atomicAdd(&cur[v & 1023], 1);
    srcs[p0 + r] = v >> 10;
  }
}

// ---------------- Block 1 (N=200000, C=16) ----------------
__global__ void k_agg1(const float4* __restrict__ feat, const int* __restrict__ srcs,
                       const int* __restrict__ off, const float* __restrict__ pos,
                       const float* __restrict__ w48, const float* __restrict__ bias,
                       float4* __restrict__ H4){
  int t = threadIdx.x;
  int eidx = t & 15;
  int d = blockIdx.x*16 + (t >> 4);
  int s0 = off[d], s1 = off[d+1];
  float NI = -__builtin_inff();
  float m[16];
  #pragma unroll
  for (int c = 0; c < 16; ++c) m[c] = NI;
  for (int j = s0 + eidx; j < s1; j += 16){
    float4 f = feat[srcs[j]];
    #pragma unroll
    for (int c = 0; c < 16; ++c)
      m[c] = fmaxf(m[c], f.x*w48[c] + f.y*w48[16+c] + f.z*w48[32+c]);
  }
  #pragma unroll
  for (int mask = 1; mask < 16; mask <<= 1){
    #pragma unroll
    for (int c = 0; c < 16; ++c) m[c] = fmaxf(m[c], __shfl_xor(m[c], mask, 64));
  }
  if (eidx == 0){
    float o[16];
    if (s1 > s0){
      float px = pos[3*d], py = pos[3*d+1];
      #pragma unroll
      for (int c = 0; c < 16; ++c) o[c] = m[c] + bias[c] - (px*w48[16+c] + py*w48[32+c]);
    } else {
      #pragma unroll
      for (int c = 0; c < 16; ++c) o[c] = 0.f;
    }
    H4[d*4+0] = make_float4(o[0],o[1],o[2],o[3]);
    H4[d*4+1] = make_float4(o[4],o[5],o[6],o[7]);
    H4[d*4+2] = make_float4(o[8],o[9],o[10],o[11]);
    H4[d*4+3] = make_float4(o[12],o[13],o[14],o[15]);
  }
}

__global__ void k_agg16w(const float4* __restrict__ A4, const int* __restrict__ srcs,
                         const int* __restrict__ off, const float* __restrict__ pos,
                         const float* __restrict__ wpos, const float* __restrict__ bias,
                         float4* __restrict__ H4){
  int t = threadIdx.x;
  int lane = t & 63;
  int d = blockIdx.x*4 + (t >> 6);
  int eidx = lane >> 2;
  int cg = lane & 3;
  int s0 = off[d], s1 = off[d+1];
  float NI = -__builtin_inff();
  float4 m = make_float4(NI, NI, NI, NI);
  for (int j = s0 + eidx; j < s1; j += 16){
    int s = srcs[j];
    float4 a = A4[s*4 + cg];
    m.x = fmaxf(m.x, a.x); m.y = fmaxf(m.y, a.y);
    m.z = fmaxf(m.z, a.z); m.w = fmaxf(m.w, a.w);
  }
  #pragma unroll
  for (int mask = 4; mask <= 32; mask <<= 1){
    m.x = fmaxf(m.x, __shfl_xor(m.x, mask, 64));
    m.y = fmaxf(m.y, __shfl_xor(m.y, mask, 64));
    m.z = fmaxf(m.z, __shfl_xor(m.z, mask, 64));
    m.w = fmaxf(m.w, __shfl_xor(m.w, mask, 64));
  }
  if (eidx == 0){
    float4 val = make_float4(0.f, 0.f, 0.f, 0.f);
    if (s1 > s0){
      float px = pos[3*d], py = pos[3*d+1];
      int c0 = cg*4;
      val.x = m.x + bias[c0+0] - (px*wpos[c0+0] + py*wpos[16+c0+0]);
      val.y = m.y + bias[c0+1] - (px*wpos[c0+1] + py*wpos[16+c0+1]);
      val.z = m.z + bias[c0+2] - (px*wpos[c0+2] + py*wpos[16+c0+2]);
      val.w = m.w + bias[c0+3] - (px*wpos[c0+3] + py*wpos[16+c0+3]);
    }
    H4[d*4 + cg] = val;
  }
}

__global__ void k_stats16(const float* __restrict__ H, float* __restrict__ st){
  int t = threadIdx.x;
  float s = 0.f, q = 0.f;
  for (int idx = blockIdx.x*256 + t; idx < NN*16; idx += gridDim.x*256){
    float v = H[idx]; s += v; q += v*v;
  }
  __shared__ float sv[256], sq[256];
  sv[t] = s; sq[t] = q; __syncthreads();
  for (int o = 128; o >= 16; o >>= 1){
    if (t < o){ sv[t]+=sv[t+o]; sq[t]+=sq[t+o]; } __syncthreads();
  }
  if (t < 16){ atomicAdd(&st[t], sv[t]); atomicAdd(&st[16+t], sq[t]); }
}

__global__ void k_prep2(const float* __restrict__ Hraw, const float* __restrict__ st1,
                        const float* __restrict__ pos, const float* __restrict__ w,
                        float4* __restrict__ A4){
  int idx = blockIdx.x*blockDim.x + threadIdx.x;
  if (idx >= NN*4) return;
  int i = idx >> 2, cg = idx & 3;
  const float inv_n = 1.f/(float)NN;
  float acc0 = 0.f, acc1 = 0.f, acc2 = 0.f, acc3 = 0.f;
  #pragma unroll
  for (int k = 0; k < 16; ++k){
    float mk = st1[k]*inv_n;
    float vk = st1[16+k]*inv_n - mk*mk;
    float ik = rsqrtf(vk + EPSV);
    float h = fmaxf((Hraw[i*16+k]-mk)*ik, 0.f);
    acc0 += h*w[k*16 + cg*4 + 0];
    acc1 += h*w[k*16 + cg*4 + 1];
    acc2 += h*w[k*16 + cg*4 + 2];
    acc3 += h*w[k*16 + cg*4 + 3];
  }
  float px = pos[3*i], py = pos[3*i+1];
  int c0 = cg*4;
  acc0 += px*w[256+c0+0] + py*w[272+c0+0];
  acc1 += px*w[256+c0+1] + py*w[272+c0+1];
  acc2 += px*w[256+c0+2] + py*w[272+c0+2];
  acc3 += px*w[256+c0+3] + py*w[272+c0+3];
  A4[idx] = make_float4(acc0, acc1, acc2, acc3);
}

__global__ void k_comb_pool(const float* __restrict__ H, const float* __restrict__ x,
                            const float* __restrict__ pos, const float* __restrict__ lw,
                            const float* __restrict__ st2, const float* __restrict__ xstats,
                            float* __restrict__ mem){
  int idx = blockIdx.x*blockDim.x + threadIdx.x;
  if (idx >= NN*4) return;
  int i = idx >> 2, cg = idx & 3;
  const float inv_n = 1.f/(float)NN;
  float mx = xstats[0]*inv_n, vx = xstats[1]*inv_n - mx*mx;
  float xc = x[i] - mx;
  float px = pos[3*i], py = pos[3*i+1];
  int cx = (int)(px * 80.f / 240.f); cx = min(max(cx,0),79);
  int cy = (int)(py * 60.f / 180.f); cy = min(max(cy,0),59);
  float* mrow = &mem[(cy*80+cx)*16 + cg*4];
  #pragma unroll
  for (int k = 0; k < 4; ++k){
    int c = cg*4 + k;
    float m2 = st2[c]*inv_n, v2 = st2[16+c]*inv_n - m2*m2;
    float i2 = rsqrtf(v2 + EPSV);
    float a = lw[c];
    float sc = a * rsqrtf(a*a*vx + EPSV);
    float v = (H[i*16+c]-m2)*i2 + xc*sc;
    v = fmaxf(v, 0.f);
    atomicAdd(&mrow[k], v);
  }
}

// ---------------- Fused tail: cached float4 reads + 8B write-through stores ----------------
// Correctness protocol: every inter-stage tensor is write-once (distinct buffer per
// stage) and written with agent-scope write-through stores -> coherent point has fresh
// data before the barrier. Readers use NORMAL cached loads: their L2 never cached the
// line before its write (write-once + kernel-boundary flush), so first touch misses
// to the coherent point and gets fresh data. Coalesced 16B loads, 8B stores.
__device__ __forceinline__ void st8(float* p, float a, float b){
  union{ unsigned long long u; float2 f; } v; v.f = make_float2(a,b);
  __hip_atomic_store((unsigned long long*)p, v.u, __ATOMIC_RELAXED, __HIP_MEMORY_SCOPE_AGENT);
}
__device__ __forceinline__ void st16(float* p, float4 v){
  st8(p, v.x, v.y); st8(p+2, v.z, v.w);
}
__device__ __forceinline__ float4 ld4(const float* p){ return *(const float4*)p; }
__device__ __forceinline__ void stwti(int* p, int v){
  __hip_atomic_store(p, v, __ATOMIC_RELAXED, __HIP_MEMORY_SCOPE_AGENT);
}
__device__ __forceinline__ int ldwti(const int* p){
  return __hip_atomic_load(p, __ATOMIC_RELAXED, __HIP_MEMORY_SCOPE_AGENT);
}

__device__ __forceinline__ void gridbar(int* flags, int gen){
  __syncthreads();
  if (threadIdx.x == 0){
    __atomic_signal_fence(__ATOMIC_SEQ_CST);
    __builtin_amdgcn_s_waitcnt(0);   // stores + atomics durable at coherent point
    __atomic_signal_fence(__ATOMIC_SEQ_CST);
    stwti(&flags[blockIdx.x], gen);
  }
  int ok;
  do {
    int mine = 1;
    for (int w = threadIdx.x; w < NWG; w += 256)
      if (ldwti(&flags[w]) < gen) mine = 0;
    ok = __syncthreads_and(mine);
    if (!ok) __builtin_amdgcn_s_sleep(1);
  } while (!ok);
}

// sum NSLOT stat copies (normal cached loads; stats lines are write(atomic)-then-read-once)
__device__ __forceinline__ float sumslots(const float* st, int twoC, int i){
  float s = 0.f;
  #pragma unroll 8
  for (int cp = 0; cp < NSLOT; ++cp) s += st[cp*twoC + i];
  return s;
}

struct TailP {
  const float *mem1;
  const float *p1w,*p1b,*p2w,*p2b,*p3w,*p3b;
  const float *c1w2,*c1b2,*c2w2,*c2b2,*lw2,*lb2;
  const float *c1w3,*c1b3,*c2w3,*c2b3,*lw3,*lb3;
  const float *c1w4,*c1b4,*c2w4,*c2b4,*lw4,*lb4;
  float *g1,*SK2,*S2a,*H2a,*S2b,*H2b,*g2p;
  float *SK3,*S3a,*H3a,*S3b,*H3b,*g3p;
  float *SK4,*S4a,*H4a,*S4b,*H4b;
  float *stB2sk,*stB2c1,*stB2c2,*stB3sk,*stB3c1,*stB3c2,*stB4sk,*stB4c1,*stB4c2;
  float *out;
  int *flags;
};

__device__ __forceinline__ void d_poollin(const float* mem, const float* W, const float* b,
                                          float* G, int n, int C, int gid, int gs){
  int CG = C >> 2;
  int N4 = n*CG;
  for (int idx = gid; idx < N4; idx += gs){
    int i = idx / CG, cg = idx - i*CG;
    float4 acc = ld4(&b[cg*4]);
    for (int k = 0; k < C; ++k){
      float xv = mem[i*C+k];
      float4 wv = ld4(&W[k*C + cg*4]);
      acc.x = fmaf(xv, wv.x, acc.x); acc.y = fmaf(xv, wv.y, acc.y);
      acc.z = fmaf(xv, wv.z, acc.z); acc.w = fmaf(xv, wv.w, acc.w);
    }
    float4 g;
    g.x = (acc.x > 1.f) ? acc.x : 0.f;
    g.y = (acc.y > 1.f) ? acc.y : 0.f;
    g.z = (acc.z > 1.f) ? acc.z : 0.f;
    g.w = (acc.w > 1.f) ? acc.w : 0.f;
    st16(&G[idx*4], g);
  }
}

__device__ __forceinline__ void d_gmm(const float* X, const float* W, const float* bias,
                                      float* S, int n, int K, int C,
                                      float* st, const float* instats,
                                      float4* sv4, float4* sq4, float* la, float* lb,
                                      int gid, int gs){
  const float inv_n = 1.f/(float)n;
  int t = threadIdx.x;
  int CG = C >> 2;
  if (instats){
    __syncthreads();
    if (t < K){
      float mk = sumslots(instats, 2*K, t)*inv_n;
      float vk = sumslots(instats, 2*K, K+t)*inv_n - mk*mk;
      float ik = rsqrtf(vk + EPSV);
      la[t] = ik; lb[t] = -mk*ik;
    }
    __syncthreads();
  }
  float4 ls = make_float4(0,0,0,0), lq = make_float4(0,0,0,0);
  int N4 = n*CG;
  for (int idx = gid; idx < N4; idx += gs){
    int i = idx / CG, cg = idx - i*CG;
    const float* Xr = &X[i*K];
    float4 acc = bias ? ld4(&bias[cg*4]) : make_float4(0,0,0,0);
    for (int k4 = 0; k4 < K; k4 += 4){
      float4 xv = ld4(&Xr[k4]);
      float xa[4] = {xv.x, xv.y, xv.z, xv.w};
      #pragma unroll
      for (int j = 0; j < 4; ++j){
        float xk = xa[j];
        int k = k4 + j;
        if (instats) xk = fmaxf(fmaf(xk, la[k], lb[k]), 0.f);
        float4 wv = ld4(&W[k*C + cg*4]);
        acc.x = fmaf(xk, wv.x, acc.x); acc.y = fmaf(xk, wv.y, acc.y);
        acc.z = fmaf(xk, wv.z, acc.z); acc.w = fmaf(xk, wv.w, acc.w);
      }
    }
    st16(&S[idx*4], acc);
    ls.x += acc.x; ls.y += acc.y; ls.z += acc.z; ls.w += acc.w;
    lq.x += acc.x*acc.x; lq.y += acc.y*acc.y; lq.z += acc.z*acc.z; lq.w += acc.w*acc.w;
  }
  if (st){
    __syncthreads();
    sv4[t] = ls; sq4[t] = lq; __syncthreads();
    for (int o = 128; o >= CG; o >>= 1){
      if (t < o){
        float4 a = sv4[t], b = sv4[t+o];
        a.x+=b.x; a.y+=b.y; a.z+=b.z; a.w+=b.w; sv4[t] = a;
        float4 c = sq4[t], d = sq4[t+o];
        c.x+=d.x; c.y+=d.y; c.z+=d.z; c.w+=d.w; sq4[t] = c;
      }
      __syncthreads();
    }
    if (t < CG){
      float* dst = &st[(blockIdx.x & (NSLOT-1))*2*C];
      float4 a = sv4[t], b = sq4[t];
      atomicAdd(&dst[t*4+0], a.x); atomicAdd(&dst[t*4+1], a.y);
      atomicAdd(&dst[t*4+2], a.z); atomicAdd(&dst[t*4+3], a.w);
      atomicAdd(&dst[C+t*4+0], b.x); atomicAdd(&dst[C+t*4+1], b.y);
      atomicAdd(&dst[C+t*4+2], b.z); atomicAdd(&dst[C+t*4+3], b.w);
    }
    __syncthreads();
  }
}

__device__ __forceinline__ void d_gridagg(const float* S, const float* wpos, const float* bias,
                                          float* H, float* st, int n, int gw, int gh, int C,
                                          float sx, float sy,
                                          float4* sv4, float4* sq4, int gid, int gs){
  int CG = C >> 2;
  float4 ls = make_float4(0,0,0,0), lq = make_float4(0,0,0,0);
  int N4 = n*CG;
  for (int idx = gid; idx < N4; idx += gs){
    int i = idx / CG, cg = idx - i*CG;
    int x = i % gw, y = i / gw;
    float4 wxv = ld4(&wpos[cg*4]);
    float4 wyv = ld4(&wpos[C + cg*4]);
    float NI = -__builtin_inff();
    float4 m = make_float4(NI, NI, NI, NI);
    for (int oy = -1; oy <= 1; ++oy){
      int ny = y + oy; if (ny < 0 || ny >= gh) continue;
      float fy = oy*sy;
      for (int ox = -1; ox <= 1; ++ox){
        int nx = x + ox; if (nx < 0 || nx >= gw) continue;
        float fx = ox*sx;
        float4 s = ld4(&S[(ny*gw+nx)*C + cg*4]);
        m.x = fmaxf(m.x, s.x + fx*wxv.x + fy*wyv.x);
        m.y = fmaxf(m.y, s.y + fx*wxv.y + fy*wyv.y);
        m.z = fmaxf(m.z, s.z + fx*wxv.z + fy*wyv.z);
        m.w = fmaxf(m.w, s.w + fx*wxv.w + fy*wyv.w);
      }
    }
    float4 bv = ld4(&bias[cg*4]);
    float4 val = make_float4(m.x+bv.x, m.y+bv.y, m.z+bv.z, m.w+bv.w);
    st16(&H[idx*4], val);
    ls.x += val.x; ls.y += val.y; ls.z += val.z; ls.w += val.w;
    lq.x += val.x*val.x; lq.y += val.y*val.y; lq.z += val.z*val.z; lq.w += val.w*val.w;
  }
  int t = threadIdx.x;
  __syncthreads();
  sv4[t] = ls; sq4[t] = lq; __syncthreads();
  for (int o = 128; o >= CG; o >>= 1){
    if (t < o){
      float4 a = sv4[t], b = sv4[t+o];
      a.x+=b.x; a.y+=b.y; a.z+=b.z; a.w+=b.w; sv4[t] = a;
      float4 c = sq4[t], d = sq4[t+o];
      c.x+=d.x; c.y+=d.y; c.z+=d.z; c.w+=d.w; sq4[t] = c;
    }
    __syncthreads();
  }
  if (t < CG){
    float* dst = &st[(blockIdx.x & (NSLOT-1))*2*C];
    float4 a = sv4[t], b = sq4[t];
    atomicAdd(&dst[t*4+0], a.x); atomicAdd(&dst[t*4+1], a.y);
    atomicAdd(&dst[t*4+2], a.z); atomicAdd(&dst[t*4+3], a.w);
    atomicAdd(&dst[C+t*4+0], b.x); atomicAdd(&dst[C+t*4+1], b.y);
    atomicAdd(&dst[C+t*4+2], b.z); atomicAdd(&dst[C+t*4+3], b.w);
  }
  __syncthreads();
}

__device__ __forceinline__ float4 bnvec(const float* st, int C, int cg, float inv_n, float4* invout){
  float s0 = sumslots(st, 2*C, cg*4+0), s1 = sumslots(st, 2*C, cg*4+1);
  float s2 = sumslots(st, 2*C, cg*4+2), s3 = sumslots(st, 2*C, cg*4+3);
  float q0 = sumslots(st, 2*C, C+cg*4+0), q1 = sumslots(st, 2*C, C+cg*4+1);
  float q2 = sumslots(st, 2*C, C+cg*4+2), q3 = sumslots(st, 2*C, C+cg*4+3);
  float4 m = make_float4(s0*inv_n, s1*inv_n, s2*inv_n, s3*inv_n);
  invout->x = rsqrtf(q0*inv_n - m.x*m.x + EPSV);
  invout->y = rsqrtf(q1*inv_n - m.y*m.y + EPSV);
  invout->z = rsqrtf(q2*inv_n - m.z*m.z + EPSV);
  invout->w = rsqrtf(q3*inv_n - m.w*m.w + EPSV);
  return m;
}

// Fused: gcombine(H,SK)->out + 2x2 pool + poollin -> Gp.
__device__ __forceinline__ void d_pool_stage(const float* H, const float* SK,
                                             const float* st2, const float* stsk,
                                             const float* W, const float* b,
                                             float* outf, float* Gp,
                                             int gw, int gh, int C,
                                             float* lmem, int nwg){
  int CG = C >> 2;
  int ow = gw >> 1;
  int ncell = ow*(gh>>1);
  int cellsPerWG = 256 / CG;
  int ntile = (ncell + cellsPerWG - 1) / cellsPerWG;
  int t = threadIdx.x;
  int cl = t / CG;
  int cg = t - cl*CG;
  const float inv_n = 1.f/(float)(gw*gh);
  float4 i2, is_;
  float4 m2 = bnvec(st2, C, cg, inv_n, &i2);
  float4 ms = bnvec(stsk, C, cg, inv_n, &is_);
  for (int tile = blockIdx.x; tile < ntile; tile += nwg){
    int cell = tile*cellsPerWG + cl;
    bool act = (cell < ncell);
    float4 sum = make_float4(0,0,0,0);
    if (act){
      int px = cell % ow, py = cell / ow;
      #pragma unroll
      for (int dy = 0; dy < 2; ++dy){
        #pragma unroll
        for (int dx = 0; dx < 2; ++dx){
          int gi = ((2*py+dy)*gw + (2*px+dx))*C + cg*4;
          float4 h = ld4(&H[gi]);
          float4 sk = ld4(&SK[gi]);
          float4 v;
          v.x = fmaxf((h.x-m2.x)*i2.x + (sk.x-ms.x)*is_.x, 0.f);
          v.y = fmaxf((h.y-m2.y)*i2.y + (sk.y-ms.y)*is_.y, 0.f);
          v.z = fmaxf((h.z-m2.z)*i2.z + (sk.z-ms.z)*is_.z, 0.f);
          v.w = fmaxf((h.w-m2.w)*i2.w + (sk.w-ms.w)*is_.w, 0.f);
          st16(&outf[gi], v);
          sum.x += v.x; sum.y += v.y; sum.z += v.z; sum.w += v.w;
        }
      }
    }
    __syncthreads();
    *(float4*)&lmem[cl*C + cg*4] = sum;
    __syncthreads();
    if (act){
      float4 acc = ld4(&b[cg*4]);
      for (int k = 0; k < C; ++k){
        float xv = lmem[cl*C + k];
        float4 wv = ld4(&W[k*C + cg*4]);
        acc.x = fmaf(xv, wv.x, acc.x); acc.y = fmaf(xv, wv.y, acc.y);
        acc.z = fmaf(xv, wv.z, acc.z); acc.w = fmaf(xv, wv.w, acc.w);
      }
      float4 g;
      g.x = (acc.x > 1.f) ? acc.x : 0.f;
      g.y = (acc.y > 1.f) ? acc.y : 0.f;
      g.z = (acc.z > 1.f) ? acc.z : 0.f;
      g.w = (acc.w > 1.f) ? acc.w : 0.f;
      st16(&Gp[cell*C + cg*4], g);
    }
  }
}

__device__ __forceinline__ void d_gcombine(const float* H, const float* SK,
                                           const float* st2, const float* stsk,
                                           float* outf, int n, int C, int gid, int gs){
  int CG = C >> 2;
  const float inv_n = 1.f/(float)n;
  int cg = gid % CG;   // gs % CG == 0 -> constant per thread
  float4 i2, is_;
  float4 m2 = bnvec(st2, C, cg, inv_n, &i2);
  float4 ms = bnvec(stsk, C, cg, inv_n, &is_);
  int N4 = n*CG;
  for (int idx = gid; idx < N4; idx += gs){
    float4 h = ld4(&H[idx*4]);
    float4 sk = ld4(&SK[idx*4]);
    float4 v;
    v.x = fmaxf((h.x-m2.x)*i2.x + (sk.x-ms.x)*is_.x, 0.f);
    v.y = fmaxf((h.y-m2.y)*i2.y + (sk.y-ms.y)*is_.y, 0.f);
    v.z = fmaxf((h.z-m2.z)*i2.z + (sk.z-ms.z)*is_.z, 0.f);
    v.w = fmaxf((h.w-m2.w)*i2.w + (sk.w-ms.w)*is_.w, 0.f);
    st16(&outf[idx*4], v);
  }
}

__global__ void __launch_bounds__(256, 4) k_tail(TailP P){
  __shared__ float4 sv4[256], sq4[256];
  __shared__ float la[128], lb[128], lmem[1024];
  const int gid = blockIdx.x*256 + threadIdx.x;
  const int gs  = NWG*256;
  int* flags = P.flags;
  int gen = 0;

  d_poollin(P.mem1, P.p1w, P.p1b, P.g1, 4800, 16, gid, gs);
  gridbar(flags, ++gen);
  // ---- block 2 (80x60, 16->32) ----
  d_gmm(P.g1, P.lw2, P.lb2, P.SK2, 4800, 16, 32, P.stB2sk, nullptr, sv4, sq4, la, lb, gid, gs);
  d_gmm(P.g1, P.c1w2, nullptr, P.S2a, 4800, 16, 32, nullptr, nullptr, sv4, sq4, la, lb, gid, gs);
  gridbar(flags, ++gen);
  d_gridagg(P.S2a, P.c1w2+16*32, P.c1b2, P.H2a, P.stB2c1, 4800, 80, 60, 32, 3.f, 3.f, sv4, sq4, gid, gs);
  gridbar(flags, ++gen);
  d_gmm(P.H2a, P.c2w2, nullptr, P.S2b, 4800, 32, 32, nullptr, P.stB2c1, sv4, sq4, la, lb, gid, gs);
  gridbar(flags, ++gen);
  d_gridagg(P.S2b, P.c2w2+32*32, P.c2b2, P.H2b, P.stB2c2, 4800, 80, 60, 32, 3.f, 3.f, sv4, sq4, gid, gs);
  gridbar(flags, ++gen);
  d_pool_stage(P.H2b, P.SK2, P.stB2c2, P.stB2sk, P.p2w, P.p2b, P.out, P.g2p, 80, 60, 32, lmem, NWG);
  gridbar(flags, ++gen);
  // ---- block 3 (40x30, 32->64) ----
  d_gmm(P.g2p, P.lw3, P.lb3, P.SK3, 1200, 32, 64, P.stB3sk, nullptr, sv4, sq4, la, lb, gid, gs);
  d_gmm(P.g2p, P.c1w3, nullptr, P.S3a, 1200, 32, 64, nullptr, nullptr, sv4, sq4, la, lb, gid, gs);
  gridbar(flags, ++gen);
  d_gridagg(P.S3a, P.c1w3+32*64, P.c1b3, P.H3a, P.stB3c1, 1200, 40, 30, 64, 6.f, 6.f, sv4, sq4, gid, gs);
  gridbar(flags, ++gen);
  d_gmm(P.H3a, P.c2w3, nullptr, P.S3b, 1200, 64, 64, nullptr, P.stB3c1, sv4, sq4, la, lb, gid, gs);
  gridbar(flags, ++gen);
  d_gridagg(P.S3b, P.c2w3+64*64, P.c2b3, P.H3b, P.stB3c2, 1200, 40, 30, 64, 6.f, 6.f, sv4, sq4, gid, gs);
  gridbar(flags, ++gen);
  d_pool_stage(P.H3b, P.SK3, P.stB3c2, P.stB3sk, P.p3w, P.p3b, P.out+153600, P.g3p, 40, 30, 64, lmem, NWG);
  gridbar(flags, ++gen);
  // ---- block 4 (20x15, 64->128) ----
  d_gmm(P.g3p, P.lw4, P.lb4, P.SK4, 300, 64, 128, P.stB4sk, nullptr, sv4, sq4, la, lb, gid, gs);
  d_gmm(P.g3p, P.c1w4, nullptr, P.S4a, 300, 64, 128, nullptr, nullptr, sv4, sq4, la, lb, gid, gs);
  gridbar(flags, ++gen);
  d_gridagg(P.S4a, P.c1w4+64*128, P.c1b4, P.H4a, P.stB4c1, 300, 20, 15, 128, 12.f, 12.f, sv4, sq4, gid, gs);
  gridbar(flags, ++gen);
  d_gmm(P.H4a, P.c2w4, nullptr, P.S4b, 300, 128, 128, nullptr, P.stB4c1, sv4, sq4, la, lb, gid, gs);
  gridbar(flags, ++gen);
  d_gridagg(P.S4b, P.c2w4+128*128, P.c2b4, P.H4b, P.stB4c2, 300, 20, 15, 128, 12.f, 12.f, sv4, sq4, gid, gs);
  gridbar(flags, ++gen);
  d_gcombine(P.H4b, P.SK4, P.stB4c2, P.stB4sk, P.out+230400, 300, 128, gid, gs);
}

extern "C" void kernel_launch(void* const* d_in, const int* in_sizes, int n_in,
                              void* d_out, int out_size, void* d_ws, size_t ws_size,
                              hipStream_t stream){
  const float* x   = (const float*)d_in[0];
  const float* pos = (const float*)d_in[1];
  const int*   ei  = (const int*)d_in[2];
  const float* b1_c1w = (const float*)d_in[3];
  const float* b1_c1b = (const float*)d_in[4];
  const float* b1_c2w = (const float*)d_in[5];
  const float* b1_c2b = (const float*)d_in[6];
  const float* b1_lw  = (const float*)d_in[7];
  const float* b2_c1w = (const float*)d_in[9];
  const float* b2_c1b = (const float*)d_in[10];
  const float* b2_c2w = (const float*)d_in[11];
  const float* b2_c2b = (const float*)d_in[12];
  const float* b2_lw  = (const float*)d_in[13];
  const float* b2_lb  = (const float*)d_in[14];
  const float* b3_c1w = (const float*)d_in[15];
  const float* b3_c1b = (const float*)d_in[16];
  const float* b3_c2w = (const float*)d_in[17];
  const float* b3_c2b = (const float*)d_in[18];
  const float* b3_lw  = (const float*)d_in[19];
  const float* b3_lb  = (const float*)d_in[20];
  const float* b4_c1w = (const float*)d_in[21];
  const float* b4_c1b = (const float*)d_in[22];
  const float* b4_c2w = (const float*)d_in[23];
  const float* b4_c2b = (const float*)d_in[24];
  const float* b4_lw  = (const float*)d_in[25];
  const float* b4_lb  = (const float*)d_in[26];
  const float* p1w = (const float*)d_in[27];
  const float* p1b = (const float*)d_in[28];
  const float* p2w = (const float*)d_in[29];
  const float* p2b = (const float*)d_in[30];
  const float* p3w = (const float*)d_in[31];
  const float* p3b = (const float*)d_in[32];
  float* out = (float*)d_out;

  // ---- workspace carve ----
  float4* feat = (float4*)d_ws;       // NN float4 (3.2MB)
  float* A  = (float*)(feat + NN);    // NN*16 fp32 = 3.2M floats
  int* pairs = (int*)A;               // NE ints — ALIAS (dead before A written)
  // tail buffers ALIAS A too (A dead before tail launches): 1.48M floats << 3.2M
  float* g1   = A;                    // 4800*16
  float* b2SK = g1 + 76800;           // 4800*32
  float* b2Sa = b2SK + 153600;
  float* b2Ha = b2Sa + 153600;
  float* b2Sb = b2Ha + 153600;
  float* b2Hb = b2Sb + 153600;
  float* g2p  = b2Hb + 153600;        // 1200*32
  float* b3SK = g2p + 38400;          // 1200*64
  float* b3Sa = b3SK + 76800;
  float* b3Ha = b3Sa + 76800;
  float* b3Sb = b3Ha + 76800;
  float* b3Hb = b3Sb + 76800;
  float* g3p  = b3Hb + 76800;         // 300*64
  float* b4SK = g3p + 19200;          // 300*128
  float* b4Sa = b4SK + 38400;
  float* b4Ha = b4Sa + 38400;
  float* b4Sb = b4Ha + 38400;
  float* b4Hb = b4Sb + 38400;
  float* H  = A + NN*16;              // NN*16
  // Z region (single memset): bucket counters, flags, stats, mem1
  int* bktCnt  = (int*)(H + NN*16);   // 256
  int* bktBase = bktCnt + 256;        // 257
  int* bktCur  = bktBase + 257;       // (pad to 1024)
  int* flags   = bktCnt + 1024;       // 768 (pad to 2048)
  float* STz   = (float*)(bktCnt + 2048);
  float* xstats = STz;                // 2
  float* st1    = STz + 16;
  float* st2    = STz + 64;           // pad to 128
  float* stB2sk = STz + 128;          // NSLOT*64 = 2048
  float* stB2c1 = STz + 2176;
  float* stB2c2 = STz + 4224;         // end 6272
  float* stB3sk = STz + 6272;         // NSLOT*128 = 4096
  float* stB3c1 = STz + 10368;
  float* stB3c2 = STz + 14464;        // end 18560
  float* stB4sk = STz + 18560;        // NSLOT*256 = 8192
  float* stB4c1 = STz + 26752;
  float* stB4c2 = STz + 34944;        // end 43136
  float* mem1   = STz + 43136;        // 76800
  const size_t ZBYTES = (size_t)(2048 + 43136 + 76800) * 4;
  int* off    = (int*)(mem1 + 76800); // NN+1
  int* srcs   = off + (NN+1);         // NE

  hipMemsetAsync(bktCnt, 0, ZBYTES, stream);

  const int B = 256;
  // CSR build (fused with feat/xstats prep)
  k_cnt_prep<<<(NE+4095)/4096, 256, 0, stream>>>(ei, bktCnt, x, pos, feat, xstats);
  k_bktscan <<<1, 256, 0, stream>>>(bktCnt, bktBase, bktCur, off);
  k_part1   <<<(NE+16383)/16384, 1024, 0, stream>>>(ei, bktCur, pairs);
  k_part2   <<<196, 1024, 0, stream>>>(pairs, bktBase, off, srcs);

  // Block 1
  k_agg1    <<<NN/16, B, 0, stream>>>(feat, srcs, off, pos, b1_c1w, b1_c1b, (float4*)H);
  k_stats16 <<<256, B, 0, stream>>>(H, st1);
  k_prep2   <<<(NN*4+B-1)/B, B, 0, stream>>>(H, st1, pos, b1_c2w, (float4*)A);
  k_agg16w  <<<NN/4, B, 0, stream>>>((const float4*)A, srcs, off, pos, b1_c2w+256, b1_c2b, (float4*)H);
  k_stats16 <<<256, B, 0, stream>>>(H, st2);
  k_comb_pool<<<(NN*4+B-1)/B, B, 0, stream>>>(H, x, pos, b1_lw, st2, xstats, mem1);

  // Fused tail: cached float4 reads + write-through stores + flag barrier
  TailP P;
  P.mem1 = mem1;
  P.p1w = p1w; P.p1b = p1b; P.p2w = p2w; P.p2b = p2b; P.p3w = p3w; P.p3b = p3b;
  P.c1w2 = b2_c1w; P.c1b2 = b2_c1b; P.c2w2 = b2_c2w; P.c2b2 = b2_c2b; P.lw2 = b2_lw; P.lb2 = b2_lb;
  P.c1w3 = b3_c1w; P.c1b3 = b3_c1b; P.c2w3 = b3_c2w; P.c2b3 = b3_c2b; P.lw3 = b3_lw; P.lb3 = b3_lb;
  P.c1w4 = b4_c1w; P.c1b4 = b4_c1b; P.c2w4 = b4_c2w; P.c2b4 = b4_c2b; P.lw4 = b4_lw; P.lb4 = b4_lb;
  P.g1 = g1; P.SK2 = b2SK; P.S2a = b2Sa; P.H2a = b2Ha; P.S2b = b2Sb; P.H2b = b2Hb; P.g2p = g2p;
  P.SK3 = b3SK; P.S3a = b3Sa; P.H3a = b3Ha; P.S3b = b3Sb; P.H3b = b3Hb; P.g3p = g3p;
  P.SK4 = b4SK; P.S4a = b4Sa; P.H4a = b4Ha; P.S4b = b4Sb; P.H4b = b4Hb;
  P.stB2sk = stB2sk; P.stB2c1 = stB2c1; P.stB2c2 = stB2c2;
  P.stB3sk = stB3sk; P.stB3c1 = stB3c1; P.stB3c2 = stB3c2;
  P.stB4sk = stB4sk; P.stB4c1 = stB4c1; P.stB4c2 = stB4c2;
  P.out = out; P.flags = flags;
  k_tail<<<NWG, 256, 0, stream>>>(P);
}

// Round 15
// 775.765 us; speedup vs baseline: 1.1601x; 1.1601x over previous
//
#include <hip/hip_runtime.h>

#define NN 200000
#define NE 3200000
#define NWG 120
static constexpr float EPSV = 1e-5f;

// ---------------- CSR build: 2-level bucket sort ----------------
__global__ void k_cnt_prep(const int* __restrict__ ei, int* __restrict__ bktCnt,
                           const float* __restrict__ x, const float* __restrict__ pos,
                           float4* __restrict__ feat, float* __restrict__ xstats){
  __shared__ int cnt[256];
  __shared__ float sv[256], sq[256];
  int t = threadIdx.x;
  cnt[t] = 0;
  int i = blockIdx.x*256 + t;
  float xf = 0.f;
  if (i < NN){
    xf = x[i];
    feat[i] = make_float4(xf, pos[3*i], pos[3*i+1], 0.f);
  }
  sv[t] = (i < NN) ? xf : 0.f;
  sq[t] = sv[t]*sv[t];
  __syncthreads();
  int tile = blockIdx.x*4096;
  #pragma unroll
  for (int k = 0; k < 16; ++k){
    int e = tile + k*256 + t;
    if (e < NE) atomicAdd(&cnt[ei[NE+e]>>10], 1);
  }
  for (int o = 128; o > 0; o >>= 1){
    __syncthreads();
    if (t < o){ sv[t]+=sv[t+o]; sq[t]+=sq[t+o]; }
  }
  __syncthreads();
  if (t == 0){ atomicAdd(&xstats[0], sv[0]); atomicAdd(&xstats[1], sq[0]); }
  if (cnt[t]) atomicAdd(&bktCnt[t], cnt[t]);
}

__global__ void k_bktscan(const int* __restrict__ bktCnt, int* __restrict__ bktBase,
                          int* __restrict__ bktCur, int* __restrict__ off){
  __shared__ int s[256];
  int t = threadIdx.x;
  int v = bktCnt[t];
  s[t] = v; __syncthreads();
  for (int o = 1; o < 256; o <<= 1){
    int xv = (t >= o) ? s[t-o] : 0;
    __syncthreads(); s[t] += xv; __syncthreads();
  }
  int excl = s[t] - v;
  bktBase[t] = excl;
  bktCur[t]  = excl;
  if (t == 0){ bktBase[256] = NE; off[NN] = NE; }
}

__global__ void k_part1(const int* __restrict__ ei, int* __restrict__ bktCur,
                        int* __restrict__ pairs){
  __shared__ int cnt[256]; __shared__ int base[256]; __shared__ int rank[256];
  int t = threadIdx.x;   // 1024 threads
  if (t < 256) cnt[t] = 0;
  __syncthreads();
  int tile = blockIdx.x*16384;
  #pragma unroll
  for (int k = 0; k < 16; ++k){
    int e = tile + k*1024 + t;
    if (e < NE) atomicAdd(&cnt[ei[NE+e]>>10], 1);
  }
  __syncthreads();
  if (t < 256){
    base[t] = cnt[t] ? atomicAdd(&bktCur[t], cnt[t]) : 0;
    rank[t] = 0;
  }
  __syncthreads();
  #pragma unroll
  for (int k = 0; k < 16; ++k){
    int e = tile + k*1024 + t;
    if (e < NE){
      int d = ei[NE+e], s = ei[e];
      int b = d >> 10;
      int r = atomicAdd(&rank[b], 1);
      pairs[base[b] + r] = (s<<10) | (d & 1023);
    }
  }
}

__global__ void k_part2(const int* __restrict__ pairs, const int* __restrict__ bktBase,
                        int* __restrict__ off, int* __restrict__ srcs){
  __shared__ int hist[1024]; __shared__ int cur[1024];
  int b = blockIdx.x, t = threadIdx.x;
  int p0 = bktBase[b], p1 = bktBase[b+1];
  int cntB = p1 - p0;
  int dstBase = b << 10;
  int width = min(1024, NN - dstBase);
  hist[t] = 0; __syncthreads();
  for (int i = t; i < cntB; i += 1024) atomicAdd(&hist[pairs[p0+i] & 1023], 1);
  __syncthreads();
  int h0 = hist[t];
  for (int o = 1; o < 1024; o <<= 1){
    int xv = (t >= o) ? hist[t-o] : 0;
    __syncthreads(); hist[t] += xv; __syncthreads();
  }
  int excl = hist[t] - h0;
  if (t < width) off[dstBase + t] = p0 + excl;
  cur[t] = excl; __syncthreads();
  for (int i = t; i < cntB; i += 1024){
    int v = pairs[p0+i];
    int r = atomicAdd(&cur[v & 1023], 1);
    srcs[p0 + r] = v >> 10;
  }
}

// ---------------- Block 1 (N=200000, C=16) ----------------
__global__ void k_agg1(const float4* __restrict__ feat, const int* __restrict__ srcs,
                       const int* __restrict__ off, const float* __restrict__ pos,
                       const float* __restrict__ w48, const float* __restrict__ bias,
                       float4* __restrict__ H4){
  int t = threadIdx.x;
  int eidx = t & 15;
  int d = blockIdx.x*16 + (t >> 4);
  int s0 = off[d], s1 = off[d+1];
  float NI = -__builtin_inff();
  float m[16];
  #pragma unroll
  for (int c = 0; c < 16; ++c) m[c] = NI;
  for (int j = s0 + eidx; j < s1; j += 16){
    float4 f = feat[srcs[j]];
    #pragma unroll
    for (int c = 0; c < 16; ++c)
      m[c] = fmaxf(m[c], f.x*w48[c] + f.y*w48[16+c] + f.z*w48[32+c]);
  }
  #pragma unroll
  for (int mask = 1; mask < 16; mask <<= 1){
    #pragma unroll
    for (int c = 0; c < 16; ++c) m[c] = fmaxf(m[c], __shfl_xor(m[c], mask, 64));
  }
  if (eidx == 0){
    float o[16];
    if (s1 > s0){
      float px = pos[3*d], py = pos[3*d+1];
      #pragma unroll
      for (int c = 0; c < 16; ++c) o[c] = m[c] + bias[c] - (px*w48[16+c] + py*w48[32+c]);
    } else {
      #pragma unroll
      for (int c = 0; c < 16; ++c) o[c] = 0.f;
    }
    H4[d*4+0] = make_float4(o[0],o[1],o[2],o[3]);
    H4[d*4+1] = make_float4(o[4],o[5],o[6],o[7]);
    H4[d*4+2] = make_float4(o[8],o[9],o[10],o[11]);
    H4[d*4+3] = make_float4(o[12],o[13],o[14],o[15]);
  }
}

__global__ void k_agg16w(const float4* __restrict__ A4, const int* __restrict__ srcs,
                         const int* __restrict__ off, const float* __restrict__ pos,
                         const float* __restrict__ wpos, const float* __restrict__ bias,
                         float4* __restrict__ H4){
  int t = threadIdx.x;
  int lane = t & 63;
  int d = blockIdx.x*4 + (t >> 6);
  int eidx = lane >> 2;
  int cg = lane & 3;
  int s0 = off[d], s1 = off[d+1];
  float NI = -__builtin_inff();
  float4 m = make_float4(NI, NI, NI, NI);
  for (int j = s0 + eidx; j < s1; j += 16){
    int s = srcs[j];
    float4 a = A4[s*4 + cg];
    m.x = fmaxf(m.x, a.x); m.y = fmaxf(m.y, a.y);
    m.z = fmaxf(m.z, a.z); m.w = fmaxf(m.w, a.w);
  }
  #pragma unroll
  for (int mask = 4; mask <= 32; mask <<= 1){
    m.x = fmaxf(m.x, __shfl_xor(m.x, mask, 64));
    m.y = fmaxf(m.y, __shfl_xor(m.y, mask, 64));
    m.z = fmaxf(m.z, __shfl_xor(m.z, mask, 64));
    m.w = fmaxf(m.w, __shfl_xor(m.w, mask, 64));
  }
  if (eidx == 0){
    float4 val = make_float4(0.f, 0.f, 0.f, 0.f);
    if (s1 > s0){
      float px = pos[3*d], py = pos[3*d+1];
      int c0 = cg*4;
      val.x = m.x + bias[c0+0] - (px*wpos[c0+0] + py*wpos[16+c0+0]);
      val.y = m.y + bias[c0+1] - (px*wpos[c0+1] + py*wpos[16+c0+1]);
      val.z = m.z + bias[c0+2] - (px*wpos[c0+2] + py*wpos[16+c0+2]);
      val.w = m.w + bias[c0+3] - (px*wpos[c0+3] + py*wpos[16+c0+3]);
    }
    H4[d*4 + cg] = val;
  }
}

__global__ void k_stats16(const float* __restrict__ H, float* __restrict__ st){
  int t = threadIdx.x;
  float s = 0.f, q = 0.f;
  for (int idx = blockIdx.x*256 + t; idx < NN*16; idx += gridDim.x*256){
    float v = H[idx]; s += v; q += v*v;
  }
  __shared__ float sv[256], sq[256];
  sv[t] = s; sq[t] = q; __syncthreads();
  for (int o = 128; o >= 16; o >>= 1){
    if (t < o){ sv[t]+=sv[t+o]; sq[t]+=sq[t+o]; } __syncthreads();
  }
  if (t < 16){ atomicAdd(&st[t], sv[t]); atomicAdd(&st[16+t], sq[t]); }
}

__global__ void k_prep2(const float* __restrict__ Hraw, const float* __restrict__ st1,
                        const float* __restrict__ pos, const float* __restrict__ w,
                        float4* __restrict__ A4){
  int idx = blockIdx.x*blockDim.x + threadIdx.x;
  if (idx >= NN*4) return;
  int i = idx >> 2, cg = idx & 3;
  const float inv_n = 1.f/(float)NN;
  float acc0 = 0.f, acc1 = 0.f, acc2 = 0.f, acc3 = 0.f;
  #pragma unroll
  for (int k = 0; k < 16; ++k){
    float mk = st1[k]*inv_n;
    float vk = st1[16+k]*inv_n - mk*mk;
    float ik = rsqrtf(vk + EPSV);
    float h = fmaxf((Hraw[i*16+k]-mk)*ik, 0.f);
    acc0 += h*w[k*16 + cg*4 + 0];
    acc1 += h*w[k*16 + cg*4 + 1];
    acc2 += h*w[k*16 + cg*4 + 2];
    acc3 += h*w[k*16 + cg*4 + 3];
  }
  float px = pos[3*i], py = pos[3*i+1];
  int c0 = cg*4;
  acc0 += px*w[256+c0+0] + py*w[272+c0+0];
  acc1 += px*w[256+c0+1] + py*w[272+c0+1];
  acc2 += px*w[256+c0+2] + py*w[272+c0+2];
  acc3 += px*w[256+c0+3] + py*w[272+c0+3];
  A4[idx] = make_float4(acc0, acc1, acc2, acc3);
}

__global__ void k_comb_pool(const float* __restrict__ H, const float* __restrict__ x,
                            const float* __restrict__ pos, const float* __restrict__ lw,
                            const float* __restrict__ st2, const float* __restrict__ xstats,
                            float* __restrict__ mem){
  int idx = blockIdx.x*blockDim.x + threadIdx.x;
  if (idx >= NN*4) return;
  int i = idx >> 2, cg = idx & 3;
  const float inv_n = 1.f/(float)NN;
  float mx = xstats[0]*inv_n, vx = xstats[1]*inv_n - mx*mx;
  float xc = x[i] - mx;
  float px = pos[3*i], py = pos[3*i+1];
  int cx = (int)(px * 80.f / 240.f); cx = min(max(cx,0),79);
  int cy = (int)(py * 60.f / 180.f); cy = min(max(cy,0),59);
  float* mrow = &mem[(cy*80+cx)*16 + cg*4];
  #pragma unroll
  for (int k = 0; k < 4; ++k){
    int c = cg*4 + k;
    float m2 = st2[c]*inv_n, v2 = st2[16+c]*inv_n - m2*m2;
    float i2 = rsqrtf(v2 + EPSV);
    float a = lw[c];
    float sc = a * rsqrtf(a*a*vx + EPSV);
    float v = (H[i*16+c]-m2)*i2 + xc*sc;
    v = fmaxf(v, 0.f);
    atomicAdd(&mrow[k], v);
  }
}

// ---------------- Fused tail: halo-recompute conv stages (9 barriers) ----------------
__device__ __forceinline__ void stwt(float* p, float v){
  __hip_atomic_store(p, v, __ATOMIC_RELAXED, __HIP_MEMORY_SCOPE_AGENT);
}
__device__ __forceinline__ float ldwt(const float* p){
  return __hip_atomic_load(p, __ATOMIC_RELAXED, __HIP_MEMORY_SCOPE_AGENT);
}
__device__ __forceinline__ void stwti(int* p, int v){
  __hip_atomic_store(p, v, __ATOMIC_RELAXED, __HIP_MEMORY_SCOPE_AGENT);
}
__device__ __forceinline__ int ldwti(const int* p){
  return __hip_atomic_load(p, __ATOMIC_RELAXED, __HIP_MEMORY_SCOPE_AGENT);
}

__device__ __forceinline__ void gridbar(int* flags, int gen){
  __syncthreads();
  if (threadIdx.x == 0){
    __atomic_signal_fence(__ATOMIC_SEQ_CST);
    __builtin_amdgcn_s_waitcnt(0);
    __atomic_signal_fence(__ATOMIC_SEQ_CST);
    stwti(&flags[blockIdx.x], gen);
  }
  int ok;
  do {
    int mine = 1;
    for (int w = threadIdx.x; w < NWG; w += 256)
      if (ldwti(&flags[w]) < gen) mine = 0;
    ok = __syncthreads_and(mine);
    if (!ok) __builtin_amdgcn_s_sleep(1);
  } while (!ok);
}

struct TailP {
  const float *mem1;
  const float *p1w,*p1b,*p2w,*p2b,*p3w,*p3b;
  const float *c1w2,*c1b2,*c2w2,*c2b2,*lw2,*lb2;
  const float *c1w3,*c1b3,*c2w3,*c2b3,*lw3,*lb3;
  const float *c1w4,*c1b4,*c2w4,*c2b4,*lw4,*lb4;
  float *g1,*SK2,*H2a,*H2b,*g2p;
  float *SK3,*H3a,*H3b,*g3p;
  float *SK4,*H4a,*H4b;
  float *stB2sk,*stB2c1,*stB2c2,*stB3sk,*stB3c1,*stB3c2,*stB4sk,*stB4c1,*stB4c2;
  float *out;
  int *flags;
};

__device__ __forceinline__ void d_poollin(const float* mem, const float* W, const float* b,
                                          float* G, int n, int C, int gid, int gs){
  for (int idx = gid; idx < n*C; idx += gs){
    int i = idx / C, c = idx % C;
    float acc = b[c];
    for (int k = 0; k < C; ++k) acc += mem[i*C+k]*W[k*C+c];
    stwt(&G[idx], (acc > 1.f) ? acc : 0.f);
  }
}

// skip-branch matmul + stats (no aggregation)
__device__ __forceinline__ void d_gmm(const float* X, const float* W, const float* bias,
                                      float* S, int n, int K, int C,
                                      float* st, float* sv, float* sq,
                                      int gid, int gs){
  int t = threadIdx.x;
  float ls = 0.f, lq = 0.f;
  for (int idx = gid; idx < n*C; idx += gs){
    int i = idx / C, c = idx % C;
    float acc = bias[c];
    for (int k = 0; k < K; ++k) acc += ldwt(&X[i*K+k])*W[k*C+c];
    stwt(&S[idx], acc);
    ls += acc; lq += acc*acc;
  }
  __syncthreads();
  sv[t] = ls; sq[t] = lq; __syncthreads();
  for (int o = 128; o >= C; o >>= 1){
    if (t < o){ sv[t]+=sv[t+o]; sq[t]+=sq[t+o]; } __syncthreads();
  }
  if (t < C){ atomicAdd(&st[t], sv[t]); atomicAdd(&st[C+t], sq[t]); }
  __syncthreads();
}

// Fused conv: per-tile gmm (with halo) into LDS, then 3x3 max agg from LDS.
// f = identity (instats==null) or relu(bn) with stats of the n=gw*gh input grid.
__device__ void d_convf(const float* X, const float* W, const float* instats,
                        const float* wpos, const float* cbias,
                        float* H, float* st,
                        int gw, int gh, int Cin, int C,
                        float sx, float sy, int tW, int tH,
                        float* Sl, float* sv, float* sq, float* la, float* lb){
  int t = threadIdx.x;
  int CG = C >> 2;
  const float inv_n = 1.f/(float)(gw*gh);
  if (instats){
    __syncthreads();
    if (t < Cin){
      float mk = ldwt(&instats[t])*inv_n;
      float vk = ldwt(&instats[Cin+t])*inv_n - mk*mk;
      float ik = rsqrtf(vk + EPSV);
      la[t] = ik; lb[t] = -mk*ik;
    }
    __syncthreads();
  }
  int hW = tW+2;
  int tilesX = (gw + tW - 1)/tW;
  int tilesY = (gh + tH - 1)/tH;
  int ntiles = tilesX*tilesY;
  float l0=0.f,l1=0.f,l2=0.f,l3=0.f,q0=0.f,q1=0.f,q2=0.f,q3=0.f;
  for (int T = blockIdx.x; T < ntiles; T += NWG){
    int tx = T % tilesX, ty = T / tilesX;
    int X0 = tx*tW - 1, Y0 = ty*tH - 1;   // halo origin
    __syncthreads();
    // phase 1: gmm into LDS over halo cells
    int nh = hW*(tH+2)*CG;
    for (int item = t; item < nh; item += 256){
      int ci = item / CG; int cgl = item % CG;
      int lx = ci % hW, ly = ci / hW;
      int gx = X0+lx, gy = Y0+ly;
      if (gx >= 0 && gx < gw && gy >= 0 && gy < gh){
        const float* Xr = &X[(gy*gw+gx)*Cin];
        const float* W0 = &W[cgl*4];
        float a0=0.f,a1=0.f,a2=0.f,a3=0.f;
        for (int k = 0; k < Cin; ++k){
          float xk = ldwt(&Xr[k]);
          if (instats) xk = fmaxf(fmaf(xk, la[k], lb[k]), 0.f);
          const float* Wr = &W0[k*C];
          a0 = fmaf(xk, Wr[0], a0); a1 = fmaf(xk, Wr[1], a1);
          a2 = fmaf(xk, Wr[2], a2); a3 = fmaf(xk, Wr[3], a3);
        }
        float* Sd = &Sl[ci*C + cgl*4];
        Sd[0]=a0; Sd[1]=a1; Sd[2]=a2; Sd[3]=a3;
      }
    }
    __syncthreads();
    // phase 2: 3x3 max agg for interior cells from LDS
    int ni = tW*tH*CG;
    for (int item = t; item < ni; item += 256){
      int ci = item / CG; int cgl = item % CG;
      int lx = ci % tW, ly = ci / tW;
      int gx = X0+1+lx, gy = Y0+1+ly;
      if (gx < gw && gy < gh){
        int c0 = cgl*4;
        float wx0=wpos[c0],wx1=wpos[c0+1],wx2=wpos[c0+2],wx3=wpos[c0+3];
        float wy0=wpos[C+c0],wy1=wpos[C+c0+1],wy2=wpos[C+c0+2],wy3=wpos[C+c0+3];
        float NI = -__builtin_inff();
        float m0=NI,m1=NI,m2=NI,m3=NI;
        for (int oy = -1; oy <= 1; ++oy){
          int ngy = gy + oy; if (ngy < 0 || ngy >= gh) continue;
          float fy = oy*sy;
          for (int ox = -1; ox <= 1; ++ox){
            int ngx = gx + ox; if (ngx < 0 || ngx >= gw) continue;
            float fx = ox*sx;
            const float* Sp = &Sl[((ly+1+oy)*hW + (lx+1+ox))*C + c0];
            m0 = fmaxf(m0, Sp[0] + fx*wx0 + fy*wy0);
            m1 = fmaxf(m1, Sp[1] + fx*wx1 + fy*wy1);
            m2 = fmaxf(m2, Sp[2] + fx*wx2 + fy*wy2);
            m3 = fmaxf(m3, Sp[3] + fx*wx3 + fy*wy3);
          }
        }
        float v0 = m0 + cbias[c0+0], v1 = m1 + cbias[c0+1];
        float v2 = m2 + cbias[c0+2], v3 = m3 + cbias[c0+3];
        int gi = (gy*gw+gx)*C + c0;
        stwt(&H[gi+0], v0); stwt(&H[gi+1], v1);
        stwt(&H[gi+2], v2); stwt(&H[gi+3], v3);
        l0 += v0; q0 += v0*v0; l1 += v1; q1 += v1*v1;
        l2 += v2; q2 += v2*v2; l3 += v3; q3 += v3*v3;
      }
    }
  }
  // stats: 4 scalar tree reductions (thread's channel-group cg = t%CG is fixed)
  float lsv[4] = {l0,l1,l2,l3}, lqv[4] = {q0,q1,q2,q3};
  #pragma unroll
  for (int j = 0; j < 4; ++j){
    __syncthreads();
    sv[t] = lsv[j]; sq[t] = lqv[j]; __syncthreads();
    for (int o = 128; o >= CG; o >>= 1){
      if (t < o){ sv[t]+=sv[t+o]; sq[t]+=sq[t+o]; } __syncthreads();
    }
    if (t < CG){ atomicAdd(&st[t*4+j], sv[t]); atomicAdd(&st[C+t*4+j], sq[t]); }
  }
  __syncthreads();
}

// Fused: gcombine(H,SK)->out + 2x2 pool + poollin -> Gp.
__device__ __forceinline__ void d_pool_stage(const float* H, const float* SK,
                                             const float* st2, const float* stsk,
                                             const float* W, const float* b,
                                             float* outf, float* Gp,
                                             int gw, int gh, int C, int PC,
                                             float* lmem, int nwg){
  int ow = gw >> 1;
  int ncell = ow*(gh>>1);
  int ntile = ncell / PC;
  int t = threadIdx.x;
  int cl = t / C;
  int c  = t % C;
  const float inv_n = 1.f/(float)(gw*gh);
  float m2 = ldwt(&st2[c])*inv_n, v2 = ldwt(&st2[C+c])*inv_n - m2*m2;
  float i2 = rsqrtf(v2 + EPSV);
  float ms = ldwt(&stsk[c])*inv_n, vs = ldwt(&stsk[C+c])*inv_n - ms*ms;
  float is_ = rsqrtf(vs + EPSV);
  for (int tile = blockIdx.x; tile < ntile; tile += nwg){
    int cell = tile*PC + cl;
    int px = cell % ow, py = cell / ow;
    float sum = 0.f;
    #pragma unroll
    for (int dy = 0; dy < 2; ++dy){
      #pragma unroll
      for (int dx = 0; dx < 2; ++dx){
        int gi = ((2*py+dy)*gw + (2*px+dx))*C + c;
        float v = (ldwt(&H[gi])-m2)*i2 + (ldwt(&SK[gi])-ms)*is_;
        v = fmaxf(v, 0.f);
        stwt(&outf[gi], v);
        sum += v;
      }
    }
    __syncthreads();
    lmem[cl*C + c] = sum;
    __syncthreads();
    float acc = b[c];
    for (int k = 0; k < C; ++k) acc += lmem[cl*C + k]*W[k*C+c];
    stwt(&Gp[cell*C + c], (acc > 1.f) ? acc : 0.f);
  }
}

__device__ __forceinline__ void d_gcombine(const float* H, const float* SK,
                                           const float* st2, const float* stsk,
                                           float* outf, int n, int C, int gid, int gs){
  const float inv_n = 1.f/(float)n;
  for (int idx = gid; idx < n*C; idx += gs){
    int c = idx % C;
    float m2 = ldwt(&st2[c])*inv_n, v2 = ldwt(&st2[C+c])*inv_n - m2*m2;
    float i2 = rsqrtf(v2 + EPSV);
    float ms = ldwt(&stsk[c])*inv_n, vs = ldwt(&stsk[C+c])*inv_n - ms*ms;
    float is_ = rsqrtf(vs + EPSV);
    float v = (ldwt(&H[idx])-m2)*i2 + (ldwt(&SK[idx])-ms)*is_;
    stwt(&outf[idx], fmaxf(v, 0.f));
  }
}

__global__ void __launch_bounds__(256) k_tail(TailP P){
  __shared__ float Sl[6400];          // max halo tile: 10x10 x 64ch = 25.6KB
  __shared__ float sv[256], sq[256], la[128], lb[128], lmem[256];
  const int gid = blockIdx.x*256 + threadIdx.x;
  const int gs  = NWG*256;
  int* flags = P.flags;
  int gen = 0;

  d_poollin(P.mem1, P.p1w, P.p1b, P.g1, 4800, 16, gid, gs);
  gridbar(flags, ++gen);
  // ---- block 2 (80x60, 16->32) ----
  d_gmm(P.g1, P.lw2, P.lb2, P.SK2, 4800, 16, 32, P.stB2sk, sv, sq, gid, gs);
  d_convf(P.g1, P.c1w2, nullptr, P.c1w2+16*32, P.c1b2, P.H2a, P.stB2c1,
          80, 60, 16, 32, 3.f, 3.f, 8, 8, Sl, sv, sq, la, lb);
  gridbar(flags, ++gen);
  d_convf(P.H2a, P.c2w2, P.stB2c1, P.c2w2+32*32, P.c2b2, P.H2b, P.stB2c2,
          80, 60, 32, 32, 3.f, 3.f, 8, 8, Sl, sv, sq, la, lb);
  gridbar(flags, ++gen);
  d_pool_stage(P.H2b, P.SK2, P.stB2c2, P.stB2sk, P.p2w, P.p2b, P.out, P.g2p, 80, 60, 32, 8, lmem, NWG);
  gridbar(flags, ++gen);
  // ---- block 3 (40x30, 32->64) ----
  d_gmm(P.g2p, P.lw3, P.lb3, P.SK3, 1200, 32, 64, P.stB3sk, sv, sq, gid, gs);
  d_convf(P.g2p, P.c1w3, nullptr, P.c1w3+32*64, P.c1b3, P.H3a, P.stB3c1,
          40, 30, 32, 64, 6.f, 6.f, 8, 8, Sl, sv, sq, la, lb);
  gridbar(flags, ++gen);
  d_convf(P.H3a, P.c2w3, P.stB3c1, P.c2w3+64*64, P.c2b3, P.H3b, P.stB3c2,
          40, 30, 64, 64, 6.f, 6.f, 8, 8, Sl, sv, sq, la, lb);
  gridbar(flags, ++gen);
  d_pool_stage(P.H3b, P.SK3, P.stB3c2, P.stB3sk, P.p3w, P.p3b, P.out+153600, P.g3p, 40, 30, 64, 4, lmem, NWG);
  gridbar(flags, ++gen);
  // ---- block 4 (20x15, 64->128) ----
  d_gmm(P.g3p, P.lw4, P.lb4, P.SK4, 300, 64, 128, P.stB4sk, sv, sq, gid, gs);
  d_convf(P.g3p, P.c1w4, nullptr, P.c1w4+64*128, P.c1b4, P.H4a, P.stB4c1,
          20, 15, 64, 128, 12.f, 12.f, 4, 4, Sl, sv, sq, la, lb);
  gridbar(flags, ++gen);
  d_convf(P.H4a, P.c2w4, P.stB4c1, P.c2w4+128*128, P.c2b4, P.H4b, P.stB4c2,
          20, 15, 128, 128, 12.f, 12.f, 4, 4, Sl, sv, sq, la, lb);
  gridbar(flags, ++gen);
  d_gcombine(P.H4b, P.SK4, P.stB4c2, P.stB4sk, P.out+230400, 300, 128, gid, gs);
}

extern "C" void kernel_launch(void* const* d_in, const int* in_sizes, int n_in,
                              void* d_out, int out_size, void* d_ws, size_t ws_size,
                              hipStream_t stream){
  const float* x   = (const float*)d_in[0];
  const float* pos = (const float*)d_in[1];
  const int*   ei  = (const int*)d_in[2];
  const float* b1_c1w = (const float*)d_in[3];
  const float* b1_c1b = (const float*)d_in[4];
  const float* b1_c2w = (const float*)d_in[5];
  const float* b1_c2b = (const float*)d_in[6];
  const float* b1_lw  = (const float*)d_in[7];
  const float* b2_c1w = (const float*)d_in[9];
  const float* b2_c1b = (const float*)d_in[10];
  const float* b2_c2w = (const float*)d_in[11];
  const float* b2_c2b = (const float*)d_in[12];
  const float* b2_lw  = (const float*)d_in[13];
  const float* b2_lb  = (const float*)d_in[14];
  const float* b3_c1w = (const float*)d_in[15];
  const float* b3_c1b = (const float*)d_in[16];
  const float* b3_c2w = (const float*)d_in[17];
  const float* b3_c2b = (const float*)d_in[18];
  const float* b3_lw  = (const float*)d_in[19];
  const float* b3_lb  = (const float*)d_in[20];
  const float* b4_c1w = (const float*)d_in[21];
  const float* b4_c1b = (const float*)d_in[22];
  const float* b4_c2w = (const float*)d_in[23];
  const float* b4_c2b = (const float*)d_in[24];
  const float* b4_lw  = (const float*)d_in[25];
  const float* b4_lb  = (const float*)d_in[26];
  const float* p1w = (const float*)d_in[27];
  const float* p1b = (const float*)d_in[28];
  const float* p2w = (const float*)d_in[29];
  const float* p2b = (const float*)d_in[30];
  const float* p3w = (const float*)d_in[31];
  const float* p3b = (const float*)d_in[32];
  float* out = (float*)d_out;

  // ---- workspace carve ----
  float4* feat = (float4*)d_ws;       // NN float4 (3.2MB)
  float* A  = (float*)(feat + NN);    // NN*16 fp32; pairs + tail buffers ALIAS (A dead then)
  int* pairs = (int*)A;               // NE ints — ALIAS
  float* g1   = A;                    // 4800*16
  float* b2SK = g1 + 76800;           // 4800*32
  float* b2Ha = b2SK + 153600;
  float* b2Hb = b2Ha + 153600;
  float* g2p  = b2Hb + 153600;        // 1200*32
  float* b3SK = g2p + 38400;          // 1200*64
  float* b3Ha = b3SK + 76800;
  float* b3Hb = b3Ha + 76800;
  float* g3p  = b3Hb + 76800;         // 300*64
  float* b4SK = g3p + 19200;          // 300*128
  float* b4Ha = b4SK + 38400;
  float* b4Hb = b4Ha + 38400;
  float* H  = A + NN*16;              // NN*16
  // Z region (single memset): bucket counters, flags, stats, mem1
  int* bktCnt  = (int*)(H + NN*16);   // 256
  int* bktBase = bktCnt + 256;        // 257
  int* bktCur  = bktBase + 257;       // (pad)
  int* flags   = bktCnt + 784;        // 128 (pad to 1024)
  float* STz   = (float*)(bktCnt + 1024);
  float* xstats = STz;                // 2
  float* st1    = STz + 16;
  float* st2    = STz + 64;
  float* stB2sk = STz + 128;
  float* stB2c1 = STz + 192;
  float* stB2c2 = STz + 256;
  float* stB3sk = STz + 320;
  float* stB3c1 = STz + 448;
  float* stB3c2 = STz + 576;
  float* stB4sk = STz + 704;
  float* stB4c1 = STz + 960;
  float* stB4c2 = STz + 1216;         // ..1471, pad to 1536
  float* mem1   = STz + 1536;         // 76800
  const size_t ZBYTES = (size_t)(1024 + 1536 + 76800) * 4;
  int* off    = (int*)(mem1 + 76800); // NN+1
  int* srcs   = off + (NN+1);         // NE

  hipMemsetAsync(bktCnt, 0, ZBYTES, stream);

  const int B = 256;
  // CSR build (fused with feat/xstats prep)
  k_cnt_prep<<<(NE+4095)/4096, 256, 0, stream>>>(ei, bktCnt, x, pos, feat, xstats);
  k_bktscan <<<1, 256, 0, stream>>>(bktCnt, bktBase, bktCur, off);
  k_part1   <<<(NE+16383)/16384, 1024, 0, stream>>>(ei, bktCur, pairs);
  k_part2   <<<196, 1024, 0, stream>>>(pairs, bktBase, off, srcs);

  // Block 1
  k_agg1    <<<NN/16, B, 0, stream>>>(feat, srcs, off, pos, b1_c1w, b1_c1b, (float4*)H);
  k_stats16 <<<256, B, 0, stream>>>(H, st1);
  k_prep2   <<<(NN*4+B-1)/B, B, 0, stream>>>(H, st1, pos, b1_c2w, (float4*)A);
  k_agg16w  <<<NN/4, B, 0, stream>>>((const float4*)A, srcs, off, pos, b1_c2w+256, b1_c2b, (float4*)H);
  k_stats16 <<<256, B, 0, stream>>>(H, st2);
  k_comb_pool<<<(NN*4+B-1)/B, B, 0, stream>>>(H, x, pos, b1_lw, st2, xstats, mem1);

  // Fused tail: halo-recompute conv stages, 9 barriers
  TailP P;
  P.mem1 = mem1;
  P.p1w = p1w; P.p1b = p1b; P.p2w = p2w; P.p2b = p2b; P.p3w = p3w; P.p3b = p3b;
  P.c1w2 = b2_c1w; P.c1b2 = b2_c1b; P.c2w2 = b2_c2w; P.c2b2 = b2_c2b; P.lw2 = b2_lw; P.lb2 = b2_lb;
  P.c1w3 = b3_c1w; P.c1b3 = b3_c1b; P.c2w3 = b3_c2w; P.c2b3 = b3_c2b; P.lw3 = b3_lw; P.lb3 = b3_lb;
  P.c1w4 = b4_c1w; P.c1b4 = b4_c1b; P.c2w4 = b4_c2w; P.c2b4 = b4_c2b; P.lw4 = b4_lw; P.lb4 = b4_lb;
  P.g1 = g1; P.SK2 = b2SK; P.H2a = b2Ha; P.H2b = b2Hb; P.g2p = g2p;
  P.SK3 = b3SK; P.H3a = b3Ha; P.H3b = b3Hb; P.g3p = g3p;
  P.SK4 = b4SK; P.H4a = b4Ha; P.H4b = b4Hb;
  P.stB2sk = stB2sk; P.stB2c1 = stB2c1; P.stB2c2 = stB2c2;
  P.stB3sk = stB3sk; P.stB3c1 = stB3c1; P.stB3c2 = stB3c2;
  P.stB4sk = stB4sk; P.stB4c1 = stB4c1; P.stB4c2 = stB4c2;
  P.out = out; P.flags = flags;
  k_tail<<<NWG, 256, 0, stream>>>(P);
}

// Round 16
// 660.707 us; speedup vs baseline: 1.3621x; 1.1741x over previous
//
#include <hip/hip_runtime.h>

#define NN 200000
#define NE 3200000
#define NWG 120
static constexpr float EPSV = 1e-5f;

// ---------------- CSR build: 2-level bucket sort ----------------
__global__ void k_cnt_prep(const int* __restrict__ ei, int* __restrict__ bktCnt,
                           const float* __restrict__ x, const float* __restrict__ pos,
                           float4* __restrict__ feat, float* __restrict__ xstats){
  __shared__ int cnt[256];
  __shared__ float sv[256], sq[256];
  int t = threadIdx.x;
  cnt[t] = 0;
  int i = blockIdx.x*256 + t;
  float xf = 0.f;
  if (i < NN){
    xf = x[i];
    feat[i] = make_float4(xf, pos[3*i], pos[3*i+1], 0.f);
  }
  sv[t] = (i < NN) ? xf : 0.f;
  sq[t] = sv[t]*sv[t];
  __syncthreads();
  int tile = blockIdx.x*4096;
  #pragma unroll
  for (int k = 0; k < 16; ++k){
    int e = tile + k*256 + t;
    if (e < NE) atomicAdd(&cnt[ei[NE+e]>>10], 1);
  }
  for (int o = 128; o > 0; o >>= 1){
    __syncthreads();
    if (t < o){ sv[t]+=sv[t+o]; sq[t]+=sq[t+o]; }
  }
  __syncthreads();
  if (t == 0){ atomicAdd(&xstats[0], sv[0]); atomicAdd(&xstats[1], sq[0]); }
  if (cnt[t]) atomicAdd(&bktCnt[t], cnt[t]);
}

__global__ void k_bktscan(const int* __restrict__ bktCnt, int* __restrict__ bktBase,
                          int* __restrict__ bktCur, int* __restrict__ off){
  __shared__ int s[256];
  int t = threadIdx.x;
  int v = bktCnt[t];
  s[t] = v; __syncthreads();
  for (int o = 1; o < 256; o <<= 1){
    int xv = (t >= o) ? s[t-o] : 0;
    __syncthreads(); s[t] += xv; __syncthreads();
  }
  int excl = s[t] - v;
  bktBase[t] = excl;
  bktCur[t]  = excl;
  if (t == 0){ bktBase[256] = NE; off[NN] = NE; }
}

__global__ void k_part1(const int* __restrict__ ei, int* __restrict__ bktCur,
                        int* __restrict__ pairs){
  __shared__ int cnt[256]; __shared__ int base[256]; __shared__ int rank[256];
  int t = threadIdx.x;   // 1024 threads
  if (t < 256) cnt[t] = 0;
  __syncthreads();
  int tile = blockIdx.x*16384;
  #pragma unroll
  for (int k = 0; k < 16; ++k){
    int e = tile + k*1024 + t;
    if (e < NE) atomicAdd(&cnt[ei[NE+e]>>10], 1);
  }
  __syncthreads();
  if (t < 256){
    base[t] = cnt[t] ? atomicAdd(&bktCur[t], cnt[t]) : 0;
    rank[t] = 0;
  }
  __syncthreads();
  #pragma unroll
  for (int k = 0; k < 16; ++k){
    int e = tile + k*1024 + t;
    if (e < NE){
      int d = ei[NE+e], s = ei[e];
      int b = d >> 10;
      int r = atomicAdd(&rank[b], 1);
      pairs[base[b] + r] = (s<<10) | (d & 1023);
    }
  }
}

__global__ void k_part2(const int* __restrict__ pairs, const int* __restrict__ bktBase,
                        int* __restrict__ off, int* __restrict__ srcs){
  __shared__ int hist[1024]; __shared__ int cur[1024];
  int b = blockIdx.x, t = threadIdx.x;
  int p0 = bktBase[b], p1 = bktBase[b+1];
  int cntB = p1 - p0;
  int dstBase = b << 10;
  int width = min(1024, NN - dstBase);
  hist[t] = 0; __syncthreads();
  for (int i = t; i < cntB; i += 1024) atomicAdd(&hist[pairs[p0+i] & 1023], 1);
  __syncthreads();
  int h0 = hist[t];
  for (int o = 1; o < 1024; o <<= 1){
    int xv = (t >= o) ? hist[t-o] : 0;
    __syncthreads(); hist[t] += xv; __syncthreads();
  }
  int excl = hist[t] - h0;
  if (t < width) off[dstBase + t] = p0 + excl;
  cur[t] = excl; __syncthreads();
  for (int i = t; i < cntB; i += 1024){
    int v = pairs[p0+i];
    int r = atomicAdd(&cur[v & 1023], 1);
    srcs[p0 + r] = v >> 10;
  }
}

// ---------------- Block 1 (N=200000, C=16) ----------------
__global__ void k_agg1(const float4* __restrict__ feat, const int* __restrict__ srcs,
                       const int* __restrict__ off, const float* __restrict__ pos,
                       const float* __restrict__ w48, const float* __restrict__ bias,
                       float4* __restrict__ H4){
  int t = threadIdx.x;
  int eidx = t & 15;
  int d = blockIdx.x*16 + (t >> 4);
  int s0 = off[d], s1 = off[d+1];
  float NI = -__builtin_inff();
  float m[16];
  #pragma unroll
  for (int c = 0; c < 16; ++c) m[c] = NI;
  for (int j = s0 + eidx; j < s1; j += 16){
    float4 f = feat[srcs[j]];
    #pragma unroll
    for (int c = 0; c < 16; ++c)
      m[c] = fmaxf(m[c], f.x*w48[c] + f.y*w48[16+c] + f.z*w48[32+c]);
  }
  #pragma unroll
  for (int mask = 1; mask < 16; mask <<= 1){
    #pragma unroll
    for (int c = 0; c < 16; ++c) m[c] = fmaxf(m[c], __shfl_xor(m[c], mask, 64));
  }
  if (eidx == 0){
    float o[16];
    if (s1 > s0){
      float px = pos[3*d], py = pos[3*d+1];
      #pragma unroll
      for (int c = 0; c < 16; ++c) o[c] = m[c] + bias[c] - (px*w48[16+c] + py*w48[32+c]);
    } else {
      #pragma unroll
      for (int c = 0; c < 16; ++c) o[c] = 0.f;
    }
    H4[d*4+0] = make_float4(o[0],o[1],o[2],o[3]);
    H4[d*4+1] = make_float4(o[4],o[5],o[6],o[7]);
    H4[d*4+2] = make_float4(o[8],o[9],o[10],o[11]);
    H4[d*4+3] = make_float4(o[12],o[13],o[14],o[15]);
  }
}

__global__ void k_agg16w(const float4* __restrict__ A4, const int* __restrict__ srcs,
                         const int* __restrict__ off, const float* __restrict__ pos,
                         const float* __restrict__ wpos, const float* __restrict__ bias,
                         float4* __restrict__ H4){
  int t = threadIdx.x;
  int lane = t & 63;
  int d = blockIdx.x*4 + (t >> 6);
  int eidx = lane >> 2;
  int cg = lane & 3;
  int s0 = off[d], s1 = off[d+1];
  float NI = -__builtin_inff();
  float4 m = make_float4(NI, NI, NI, NI);
  for (int j = s0 + eidx; j < s1; j += 16){
    int s = srcs[j];
    float4 a = A4[s*4 + cg];
    m.x = fmaxf(m.x, a.x); m.y = fmaxf(m.y, a.y);
    m.z = fmaxf(m.z, a.z); m.w = fmaxf(m.w, a.w);
  }
  #pragma unroll
  for (int mask = 4; mask <= 32; mask <<= 1){
    m.x = fmaxf(m.x, __shfl_xor(m.x, mask, 64));
    m.y = fmaxf(m.y, __shfl_xor(m.y, mask, 64));
    m.z = fmaxf(m.z, __shfl_xor(m.z, mask, 64));
    m.w = fmaxf(m.w, __shfl_xor(m.w, mask, 64));
  }
  if (eidx == 0){
    float4 val = make_float4(0.f, 0.f, 0.f, 0.f);
    if (s1 > s0){
      float px = pos[3*d], py = pos[3*d+1];
      int c0 = cg*4;
      val.x = m.x + bias[c0+0] - (px*wpos[c0+0] + py*wpos[16+c0+0]);
      val.y = m.y + bias[c0+1] - (px*wpos[c0+1] + py*wpos[16+c0+1]);
      val.z = m.z + bias[c0+2] - (px*wpos[c0+2] + py*wpos[16+c0+2]);
      val.w = m.w + bias[c0+3] - (px*wpos[c0+3] + py*wpos[16+c0+3]);
    }
    H4[d*4 + cg] = val;
  }
}

__global__ void k_stats16(const float* __restrict__ H, float* __restrict__ st){
  int t = threadIdx.x;
  float s = 0.f, q = 0.f;
  for (int idx = blockIdx.x*256 + t; idx < NN*16; idx += gridDim.x*256){
    float v = H[idx]; s += v; q += v*v;
  }
  __shared__ float sv[256], sq[256];
  sv[t] = s; sq[t] = q; __syncthreads();
  for (int o = 128; o >= 16; o >>= 1){
    if (t < o){ sv[t]+=sv[t+o]; sq[t]+=sq[t+o]; } __syncthreads();
  }
  if (t < 16){ atomicAdd(&st[t], sv[t]); atomicAdd(&st[16+t], sq[t]); }
}

__global__ void k_prep2(const float* __restrict__ Hraw, const float* __restrict__ st1,
                        const float* __restrict__ pos, const float* __restrict__ w,
                        float4* __restrict__ A4){
  int idx = blockIdx.x*blockDim.x + threadIdx.x;
  if (idx >= NN*4) return;
  int i = idx >> 2, cg = idx & 3;
  const float inv_n = 1.f/(float)NN;
  float acc0 = 0.f, acc1 = 0.f, acc2 = 0.f, acc3 = 0.f;
  #pragma unroll
  for (int k = 0; k < 16; ++k){
    float mk = st1[k]*inv_n;
    float vk = st1[16+k]*inv_n - mk*mk;
    float ik = rsqrtf(vk + EPSV);
    float h = fmaxf((Hraw[i*16+k]-mk)*ik, 0.f);
    acc0 += h*w[k*16 + cg*4 + 0];
    acc1 += h*w[k*16 + cg*4 + 1];
    acc2 += h*w[k*16 + cg*4 + 2];
    acc3 += h*w[k*16 + cg*4 + 3];
  }
  float px = pos[3*i], py = pos[3*i+1];
  int c0 = cg*4;
  acc0 += px*w[256+c0+0] + py*w[272+c0+0];
  acc1 += px*w[256+c0+1] + py*w[272+c0+1];
  acc2 += px*w[256+c0+2] + py*w[272+c0+2];
  acc3 += px*w[256+c0+3] + py*w[272+c0+3];
  A4[idx] = make_float4(acc0, acc1, acc2, acc3);
}

__global__ void k_comb_pool(const float* __restrict__ H, const float* __restrict__ x,
                            const float* __restrict__ pos, const float* __restrict__ lw,
                            const float* __restrict__ st2, const float* __restrict__ xstats,
                            float* __restrict__ mem){
  int idx = blockIdx.x*blockDim.x + threadIdx.x;
  if (idx >= NN*4) return;
  int i = idx >> 2, cg = idx & 3;
  const float inv_n = 1.f/(float)NN;
  float mx = xstats[0]*inv_n, vx = xstats[1]*inv_n - mx*mx;
  float xc = x[i] - mx;
  float px = pos[3*i], py = pos[3*i+1];
  int cx = (int)(px * 80.f / 240.f); cx = min(max(cx,0),79);
  int cy = (int)(py * 60.f / 180.f); cy = min(max(cy,0),59);
  float* mrow = &mem[(cy*80+cx)*16 + cg*4];
  #pragma unroll
  for (int k = 0; k < 4; ++k){
    int c = cg*4 + k;
    float m2 = st2[c]*inv_n, v2 = st2[16+c]*inv_n - m2*m2;
    float i2 = rsqrtf(v2 + EPSV);
    float a = lw[c];
    float sc = a * rsqrtf(a*a*vx + EPSV);
    float v = (H[i*16+c]-m2)*i2 + xc*sc;
    v = fmaxf(v, 0.f);
    atomicAdd(&mrow[k], v);
  }
}

// ---------------- Fused tail: fence-free coherence + atomic-tree barrier (round-10 best) ----
__device__ __forceinline__ void stwt(float* p, float v){
  __hip_atomic_store(p, v, __ATOMIC_RELAXED, __HIP_MEMORY_SCOPE_AGENT);
}
__device__ __forceinline__ float ldwt(const float* p){
  return __hip_atomic_load(p, __ATOMIC_RELAXED, __HIP_MEMORY_SCOPE_AGENT);
}

// bar layout (ints, zeroed each launch): [0..255] 8 slots stride 32; [256] master; [288] generation
__device__ __forceinline__ void gridbar(int* bar){
  __syncthreads();
  if (threadIdx.x == 0){
    __atomic_signal_fence(__ATOMIC_SEQ_CST);
    __builtin_amdgcn_s_waitcnt(0);   // all write-through stores durable at coherent point
    __atomic_signal_fence(__ATOMIC_SEQ_CST);
    int g = __hip_atomic_load(bar+288, __ATOMIC_RELAXED, __HIP_MEMORY_SCOPE_AGENT);
    int slot = blockIdx.x & 7;
    int a = __hip_atomic_fetch_add(bar + slot*32, 1, __ATOMIC_RELAXED, __HIP_MEMORY_SCOPE_AGENT);
    bool released = false;
    if (a == (NWG/8 - 1)){
      int m = __hip_atomic_fetch_add(bar + 256, 1, __ATOMIC_RELAXED, __HIP_MEMORY_SCOPE_AGENT);
      if (m == 7){
        #pragma unroll
        for (int s = 0; s < 8; ++s)
          __hip_atomic_store(bar + s*32, 0, __ATOMIC_RELAXED, __HIP_MEMORY_SCOPE_AGENT);
        __hip_atomic_store(bar + 256, 0, __ATOMIC_RELAXED, __HIP_MEMORY_SCOPE_AGENT);
        __atomic_signal_fence(__ATOMIC_SEQ_CST);
        __builtin_amdgcn_s_waitcnt(0);   // zeroing durable BEFORE generation bump
        __atomic_signal_fence(__ATOMIC_SEQ_CST);
        __hip_atomic_fetch_add(bar + 288, 1, __ATOMIC_RELAXED, __HIP_MEMORY_SCOPE_AGENT);
        released = true;
      }
    }
    if (!released){
      while (__hip_atomic_load(bar+288, __ATOMIC_RELAXED, __HIP_MEMORY_SCOPE_AGENT) == g)
        __builtin_amdgcn_s_sleep(2);
    }
  }
  __syncthreads();
}

struct TailP {
  const float *mem1;
  const float *p1w,*p1b,*p2w,*p2b,*p3w,*p3b;
  const float *c1w2,*c1b2,*c2w2,*c2b2,*lw2,*lb2;
  const float *c1w3,*c1b3,*c2w3,*c2b3,*lw3,*lb3;
  const float *c1w4,*c1b4,*c2w4,*c2b4,*lw4,*lb4;
  float *g1,*S2,*SK2,*H2,*g2p;
  float *S3,*SK3,*H3,*g3p;
  float *S4,*SK4,*H4;
  float *stB2sk,*stB2c1,*stB2c2,*stB3sk,*stB3c1,*stB3c2,*stB4sk,*stB4c1,*stB4c2;
  float *out;
  int *bar;
};

__device__ __forceinline__ void d_poollin(const float* mem, const float* W, const float* b,
                                          float* G, int n, int C, int gid, int gs){
  for (int idx = gid; idx < n*C; idx += gs){
    int i = idx / C, c = idx % C;
    float acc = b[c];
    for (int k = 0; k < C; ++k) acc += mem[i*C+k]*W[k*C+c];
    stwt(&G[idx], (acc > 1.f) ? acc : 0.f);
  }
}

__device__ __forceinline__ void d_gmm(const float* X, const float* W, const float* bias,
                                      float* S, int n, int K, int C,
                                      float* st, const float* instats,
                                      float* sv, float* sq, float* la, float* lb,
                                      int gid, int gs){
  const float inv_n = 1.f/(float)n;
  int t = threadIdx.x;
  if (instats){
    __syncthreads();
    if (t < K){
      float mk = ldwt(&instats[t])*inv_n;
      float vk = ldwt(&instats[K+t])*inv_n - mk*mk;
      float ik = rsqrtf(vk + EPSV);
      la[t] = ik; lb[t] = -mk*ik;
    }
    __syncthreads();
  }
  float ls = 0.f, lq = 0.f;
  for (int idx = gid; idx < n*C; idx += gs){
    int i = idx / C, c = idx % C;
    float acc = bias ? bias[c] : 0.f;
    for (int k = 0; k < K; ++k){
      float xk = ldwt(&X[i*K+k]);
      if (instats) xk = fmaxf(fmaf(xk, la[k], lb[k]), 0.f);
      acc += xk*W[k*C+c];
    }
    stwt(&S[idx], acc);
    ls += acc; lq += acc*acc;
  }
  if (st){
    __syncthreads();
    sv[t] = ls; sq[t] = lq; __syncthreads();
    for (int o = 128; o >= C; o >>= 1){
      if (t < o){ sv[t]+=sv[t+o]; sq[t]+=sq[t+o]; } __syncthreads();
    }
    if (t < C){ atomicAdd(&st[t], sv[t]); atomicAdd(&st[C+t], sq[t]); }
    __syncthreads();
  }
}

__device__ __forceinline__ void d_gridagg(const float* S, const float* wpos, const float* bias,
                                          float* H, float* st, int n, int gw, int gh, int C,
                                          float sx, float sy,
                                          float* sv, float* sq, int gid, int gs){
  float ls = 0.f, lq = 0.f;
  for (int idx = gid; idx < n*C; idx += gs){
    int i = idx / C, c = idx % C;
    int x = i % gw, y = i / gw;
    float wx = wpos[c], wy = wpos[C+c];
    float m = -__builtin_inff();
    for (int oy = -1; oy <= 1; ++oy){
      int ny = y + oy; if (ny < 0 || ny >= gh) continue;
      for (int ox = -1; ox <= 1; ++ox){
        int nx = x + ox; if (nx < 0 || nx >= gw) continue;
        float v = ldwt(&S[(ny*gw+nx)*C + c]) + (ox*sx)*wx + (oy*sy)*wy;
        m = fmaxf(m, v);
      }
    }
    float val = m + bias[c];
    stwt(&H[idx], val);
    ls += val; lq += val*val;
  }
  int t = threadIdx.x;
  __syncthreads();
  sv[t] = ls; sq[t] = lq; __syncthreads();
  for (int o = 128; o >= C; o >>= 1){
    if (t < o){ sv[t]+=sv[t+o]; sq[t]+=sq[t+o]; } __syncthreads();
  }
  if (t < C){ atomicAdd(&st[t], sv[t]); atomicAdd(&st[C+t], sq[t]); }
  __syncthreads();
}

// Fused: gcombine(H,SK)->out + 2x2 pool + poollin -> Gp. One WG owns PC pooled cells.
__device__ __forceinline__ void d_pool_stage(const float* H, const float* SK,
                                             const float* st2, const float* stsk,
                                             const float* W, const float* b,
                                             float* outf, float* Gp,
                                             int gw, int gh, int C, int PC,
                                             float* lmem, int nwg){
  int ow = gw >> 1;
  int ncell = ow*(gh>>1);
  int ntile = ncell / PC;
  int t = threadIdx.x;
  int cl = t / C;
  int c  = t % C;
  const float inv_n = 1.f/(float)(gw*gh);
  float m2 = ldwt(&st2[c])*inv_n, v2 = ldwt(&st2[C+c])*inv_n - m2*m2;
  float i2 = rsqrtf(v2 + EPSV);
  float ms = ldwt(&stsk[c])*inv_n, vs = ldwt(&stsk[C+c])*inv_n - ms*ms;
  float is_ = rsqrtf(vs + EPSV);
  for (int tile = blockIdx.x; tile < ntile; tile += nwg){
    int cell = tile*PC + cl;
    int px = cell % ow, py = cell / ow;
    float sum = 0.f;
    #pragma unroll
    for (int dy = 0; dy < 2; ++dy){
      #pragma unroll
      for (int dx = 0; dx < 2; ++dx){
        int gi = ((2*py+dy)*gw + (2*px+dx))*C + c;
        float v = (ldwt(&H[gi])-m2)*i2 + (ldwt(&SK[gi])-ms)*is_;
        v = fmaxf(v, 0.f);
        stwt(&outf[gi], v);
        sum += v;
      }
    }
    __syncthreads();
    lmem[cl*C + c] = sum;
    __syncthreads();
    float acc = b[c];
    for (int k = 0; k < C; ++k) acc += lmem[cl*C + k]*W[k*C+c];
    stwt(&Gp[cell*C + c], (acc > 1.f) ? acc : 0.f);
  }
}

__device__ __forceinline__ void d_gcombine(const float* H, const float* SK,
                                           const float* st2, const float* stsk,
                                           float* outf, int n, int C, int gid, int gs){
  const float inv_n = 1.f/(float)n;
  for (int idx = gid; idx < n*C; idx += gs){
    int c = idx % C;
    float m2 = ldwt(&st2[c])*inv_n, v2 = ldwt(&st2[C+c])*inv_n - m2*m2;
    float i2 = rsqrtf(v2 + EPSV);
    float ms = ldwt(&stsk[c])*inv_n, vs = ldwt(&stsk[C+c])*inv_n - ms*ms;
    float is_ = rsqrtf(vs + EPSV);
    float v = (ldwt(&H[idx])-m2)*i2 + (ldwt(&SK[idx])-ms)*is_;
    stwt(&outf[idx], fmaxf(v, 0.f));
  }
}

__global__ void __launch_bounds__(256) k_tail(TailP P){
  __shared__ float sv[256], sq[256], la[128], lb[128], lmem[256];
  const int gid = blockIdx.x*256 + threadIdx.x;
  const int gs  = NWG*256;
  int* bar = P.bar;

  d_poollin(P.mem1, P.p1w, P.p1b, P.g1, 4800, 16, gid, gs);
  gridbar(bar);
  // ---- block 2 (80x60, 16->32) ----
  d_gmm(P.g1, P.lw2, P.lb2, P.SK2, 4800, 16, 32, P.stB2sk, nullptr, sv, sq, la, lb, gid, gs);
  d_gmm(P.g1, P.c1w2, nullptr, P.S2, 4800, 16, 32, nullptr, nullptr, sv, sq, la, lb, gid, gs);
  gridbar(bar);
  d_gridagg(P.S2, P.c1w2+16*32, P.c1b2, P.H2, P.stB2c1, 4800, 80, 60, 32, 3.f, 3.f, sv, sq, gid, gs);
  gridbar(bar);
  d_gmm(P.H2, P.c2w2, nullptr, P.S2, 4800, 32, 32, nullptr, P.stB2c1, sv, sq, la, lb, gid, gs);
  gridbar(bar);
  d_gridagg(P.S2, P.c2w2+32*32, P.c2b2, P.H2, P.stB2c2, 4800, 80, 60, 32, 3.f, 3.f, sv, sq, gid, gs);
  gridbar(bar);
  d_pool_stage(P.H2, P.SK2, P.stB2c2, P.stB2sk, P.p2w, P.p2b, P.out, P.g2p, 80, 60, 32, 8, lmem, NWG);
  gridbar(bar);
  // ---- block 3 (40x30, 32->64) ----
  d_gmm(P.g2p, P.lw3, P.lb3, P.SK3, 1200, 32, 64, P.stB3sk, nullptr, sv, sq, la, lb, gid, gs);
  d_gmm(P.g2p, P.c1w3, nullptr, P.S3, 1200, 32, 64, nullptr, nullptr, sv, sq, la, lb, gid, gs);
  gridbar(bar);
  d_gridagg(P.S3, P.c1w3+32*64, P.c1b3, P.H3, P.stB3c1, 1200, 40, 30, 64, 6.f, 6.f, sv, sq, gid, gs);
  gridbar(bar);
  d_gmm(P.H3, P.c2w3, nullptr, P.S3, 1200, 64, 64, nullptr, P.stB3c1, sv, sq, la, lb, gid, gs);
  gridbar(bar);
  d_gridagg(P.S3, P.c2w3+64*64, P.c2b3, P.H3, P.stB3c2, 1200, 40, 30, 64, 6.f, 6.f, sv, sq, gid, gs);
  gridbar(bar);
  d_pool_stage(P.H3, P.SK3, P.stB3c2, P.stB3sk, P.p3w, P.p3b, P.out+153600, P.g3p, 40, 30, 64, 4, lmem, NWG);
  gridbar(bar);
  // ---- block 4 (20x15, 64->128) ----
  d_gmm(P.g3p, P.lw4, P.lb4, P.SK4, 300, 64, 128, P.stB4sk, nullptr, sv, sq, la, lb, gid, gs);
  d_gmm(P.g3p, P.c1w4, nullptr, P.S4, 300, 64, 128, nullptr, nullptr, sv, sq, la, lb, gid, gs);
  gridbar(bar);
  d_gridagg(P.S4, P.c1w4+64*128, P.c1b4, P.H4, P.stB4c1, 300, 20, 15, 128, 12.f, 12.f, sv, sq, gid, gs);
  gridbar(bar);
  d_gmm(P.H4, P.c2w4, nullptr, P.S4, 300, 128, 128, nullptr, P.stB4c1, sv, sq, la, lb, gid, gs);
  gridbar(bar);
  d_gridagg(P.S4, P.c2w4+128*128, P.c2b4, P.H4, P.stB4c2, 300, 20, 15, 128, 12.f, 12.f, sv, sq, gid, gs);
  gridbar(bar);
  d_gcombine(P.H4, P.SK4, P.stB4c2, P.stB4sk, P.out+230400, 300, 128, gid, gs);
}

extern "C" void kernel_launch(void* const* d_in, const int* in_sizes, int n_in,
                              void* d_out, int out_size, void* d_ws, size_t ws_size,
                              hipStream_t stream){
  const float* x   = (const float*)d_in[0];
  const float* pos = (const float*)d_in[1];
  const int*   ei  = (const int*)d_in[2];
  const float* b1_c1w = (const float*)d_in[3];
  const float* b1_c1b = (const float*)d_in[4];
  const float* b1_c2w = (const float*)d_in[5];
  const float* b1_c2b = (const float*)d_in[6];
  const float* b1_lw  = (const float*)d_in[7];
  const float* b2_c1w = (const float*)d_in[9];
  const float* b2_c1b = (const float*)d_in[10];
  const float* b2_c2w = (const float*)d_in[11];
  const float* b2_c2b = (const float*)d_in[12];
  const float* b2_lw  = (const float*)d_in[13];
  const float* b2_lb  = (const float*)d_in[14];
  const float* b3_c1w = (const float*)d_in[15];
  const float* b3_c1b = (const float*)d_in[16];
  const float* b3_c2w = (const float*)d_in[17];
  const float* b3_c2b = (const float*)d_in[18];
  const float* b3_lw  = (const float*)d_in[19];
  const float* b3_lb  = (const float*)d_in[20];
  const float* b4_c1w = (const float*)d_in[21];
  const float* b4_c1b = (const float*)d_in[22];
  const float* b4_c2w = (const float*)d_in[23];
  const float* b4_c2b = (const float*)d_in[24];
  const float* b4_lw  = (const float*)d_in[25];
  const float* b4_lb  = (const float*)d_in[26];
  const float* p1w = (const float*)d_in[27];
  const float* p1b = (const float*)d_in[28];
  const float* p2w = (const float*)d_in[29];
  const float* p2b = (const float*)d_in[30];
  const float* p3w = (const float*)d_in[31];
  const float* p3b = (const float*)d_in[32];
  float* out = (float*)d_out;

  // ---- workspace carve ----
  float4* feat = (float4*)d_ws;       // NN float4 (3.2MB)
  float* A  = (float*)(feat + NN);    // NN*16 fp32; pairs + tail buffers ALIAS (A dead then)
  int* pairs = (int*)A;               // NE ints — ALIAS
  float* g1   = A;                    // 4800*16
  float* b2S  = g1 + 76800;           // 4800*32
  float* b2SK = b2S + 153600;
  float* b2H  = b2SK + 153600;
  float* g2p  = b2H + 153600;         // 1200*32
  float* b3S  = g2p + 38400;          // 1200*64
  float* b3SK = b3S + 76800;
  float* b3H  = b3SK + 76800;
  float* g3p  = b3H + 76800;          // 300*64
  float* b4S  = g3p + 19200;          // 300*128
  float* b4SK = b4S + 38400;
  float* b4H  = b4SK + 38400;
  float* H  = A + NN*16;              // NN*16
  // Z region (single memset): bucket counters, barrier, block-1 stats, mem1
  int* bktCnt  = (int*)(H + NN*16);   // 256
  int* bktBase = bktCnt + 256;        // 257
  int* bktCur  = bktBase + 257;       // ends 769, pad to 1024
  int* bar     = bktCnt + 1024;       // 320 (pad to 2048)
  float* STz   = (float*)(bktCnt + 2048);
  float* xstats = STz;                // 2
  float* st1    = STz + 16;
  float* st2    = STz + 64;
  float* stB2sk = STz + 128;
  float* stB2c1 = STz + 192;
  float* stB2c2 = STz + 256;
  float* stB3sk = STz + 320;
  float* stB3c1 = STz + 448;
  float* stB3c2 = STz + 576;
  float* stB4sk = STz + 704;
  float* stB4c1 = STz + 960;
  float* stB4c2 = STz + 1216;         // ..1471, pad to 1536
  float* mem1   = STz + 1536;         // 76800
  const size_t ZBYTES = (size_t)(2048 + 1536 + 76800) * 4;
  int* off    = (int*)(mem1 + 76800); // NN+1
  int* srcs   = off + (NN+1);         // NE

  hipMemsetAsync(bktCnt, 0, ZBYTES, stream);

  const int B = 256;
  // CSR build (fused with feat/xstats prep)
  k_cnt_prep<<<(NE+4095)/4096, 256, 0, stream>>>(ei, bktCnt, x, pos, feat, xstats);
  k_bktscan <<<1, 256, 0, stream>>>(bktCnt, bktBase, bktCur, off);
  k_part1   <<<(NE+16383)/16384, 1024, 0, stream>>>(ei, bktCur, pairs);
  k_part2   <<<196, 1024, 0, stream>>>(pairs, bktBase, off, srcs);

  // Block 1
  k_agg1    <<<NN/16, B, 0, stream>>>(feat, srcs, off, pos, b1_c1w, b1_c1b, (float4*)H);
  k_stats16 <<<256, B, 0, stream>>>(H, st1);
  k_prep2   <<<(NN*4+B-1)/B, B, 0, stream>>>(H, st1, pos, b1_c2w, (float4*)A);
  k_agg16w  <<<NN/4, B, 0, stream>>>((const float4*)A, srcs, off, pos, b1_c2w+256, b1_c2b, (float4*)H);
  k_stats16 <<<256, B, 0, stream>>>(H, st2);
  k_comb_pool<<<(NN*4+B-1)/B, B, 0, stream>>>(H, x, pos, b1_lw, st2, xstats, mem1);

  // Fused tail: round-10 atomic-tree fence-free barrier (fastest measured), atomic stats
  TailP P;
  P.mem1 = mem1;
  P.p1w = p1w; P.p1b = p1b; P.p2w = p2w; P.p2b = p2b; P.p3w = p3w; P.p3b = p3b;
  P.c1w2 = b2_c1w; P.c1b2 = b2_c1b; P.c2w2 = b2_c2w; P.c2b2 = b2_c2b; P.lw2 = b2_lw; P.lb2 = b2_lb;
  P.c1w3 = b3_c1w; P.c1b3 = b3_c1b; P.c2w3 = b3_c2w; P.c2b3 = b3_c2b; P.lw3 = b3_lw; P.lb3 = b3_lb;
  P.c1w4 = b4_c1w; P.c1b4 = b4_c1b; P.c2w4 = b4_c2w; P.c2b4 = b4_c2b; P.lw4 = b4_lw; P.lb4 = b4_lb;
  P.g1 = g1; P.S2 = b2S; P.SK2 = b2SK; P.H2 = b2H; P.g2p = g2p;
  P.S3 = b3S; P.SK3 = b3SK; P.H3 = b3H; P.g3p = g3p;
  P.S4 = b4S; P.SK4 = b4SK; P.H4 = b4H;
  P.stB2sk = stB2sk; P.stB2c1 = stB2c1; P.stB2c2 = stB2c2;
  P.stB3sk = stB3sk; P.stB3c1 = stB3c1; P.stB3c2 = stB3c2;
  P.stB4sk = stB4sk; P.stB4c1 = stB4c1; P.stB4c2 = stB4c2;
  P.out = out; P.bar = bar;
  k_tail<<<NWG, 256, 0, stream>>>(P);
}